// Round 8
// baseline (592.330 us; speedup 1.0000x reference)
//
#include <hip/hip_runtime.h>

#define N_NODES 200000
#define N_EDGES 1200000
#define F_IN    64
#define F_H     128
#define BN_EPS  1e-5f
#define NBUK    196          // ceil(N/1024) dst-buckets of 1024 nodes
#define BINB    293          // ceil(E/4096) bin blocks
#define FROWS   64           // rows per fused block (16 rows/wave)

typedef short bf16x8 __attribute__((ext_vector_type(8)));   // 8 bf16 in 4 VGPRs
typedef float f32x4  __attribute__((ext_vector_type(4)));
typedef unsigned short us4 __attribute__((ext_vector_type(4)));

__device__ __forceinline__ unsigned short f2bf(float f) {
    union { float f; unsigned u; } v; v.f = f;
    unsigned r = (v.u + 0x7FFFu + ((v.u >> 16) & 1u)) >> 16;  // RNE
    return (unsigned short)r;
}
__device__ __forceinline__ float bf2f(unsigned short b) {
    union { unsigned u; float f; } v; v.u = ((unsigned)b) << 16;
    return v.f;
}

// 16B global->LDS DMA: per-lane global addr, LDS dest = uniform base + lane*16.
__device__ __forceinline__ void gload_lds16(const void* g, void* l) {
    __builtin_amdgcn_global_load_lds(
        (const __attribute__((address_space(1))) void*)g,
        (__attribute__((address_space(3))) void*)l, 16, 0, 0);
}

// ---------------------------------------------------------------------------
// Weight pack into bf16 MFMA B-fragment order for mfma_f32_16x16x32_bf16.
// ---------------------------------------------------------------------------
__global__ void pack_weights_kernel(const float* __restrict__ W,
                                    const float* __restrict__ kscale,
                                    short* __restrict__ P, int KT)
{
    int t = blockIdx.x * 256 + threadIdx.x;            // over 8*KT*64
    if (t >= 8 * KT * 64) return;
    int lane = t & 63;
    int kt   = (t >> 6) % KT;
    int nt   = t / (64 * KT);
    int k0   = kt * 32 + (lane >> 4) * 8;
    int n    = nt * 16 + (lane & 15);
#pragma unroll
    for (int j = 0; j < 8; ++j) {
        float w = W[(size_t)(k0 + j) * 128 + n];
        if (kscale) w *= kscale[k0 + j];
        P[(size_t)t * 8 + j] = (short)f2bf(w);
    }
}

// ---------------------------------------------------------------------------
// CSR build: histogram -> 2-level exclusive scan over deg -> bucketed fill
// ---------------------------------------------------------------------------
__global__ __launch_bounds__(256) void hist_kernel(const int* __restrict__ ei,
                                                   int* __restrict__ deg, int E)
{
    int e = blockIdx.x * 256 + threadIdx.x;
    if (e < E) atomicAdd(&deg[ei[E + e]], 1);
}

__global__ __launch_bounds__(256) void scan1_kernel(const int* __restrict__ deg,
        int* __restrict__ part, int* __restrict__ bsum, int n)
{
    __shared__ int s[256];
    int t = threadIdx.x;
    int base = blockIdx.x * 1024 + t * 4;
    int v[4];
#pragma unroll
    for (int j = 0; j < 4; ++j) v[j] = (base + j < n) ? deg[base + j] : 0;
    int tsum = v[0] + v[1] + v[2] + v[3];
    s[t] = tsum;
    __syncthreads();
    for (int off = 1; off < 256; off <<= 1) {
        int xv = (t >= off) ? s[t - off] : 0;
        __syncthreads();
        s[t] += xv;
        __syncthreads();
    }
    int excl = s[t] - tsum;
#pragma unroll
    for (int j = 0; j < 4; ++j) {
        if (base + j < n) part[base + j] = excl;
        excl += v[j];
    }
    if (t == 255) bsum[blockIdx.x] = s[255];
}

__global__ void scan2_kernel(int* __restrict__ bsum, int nb)
{
    __shared__ int s[256];
    int t = threadIdx.x;
    int v = (t < nb) ? bsum[t] : 0;
    s[t] = v;
    __syncthreads();
    for (int off = 1; off < 256; off <<= 1) {
        int xv = (t >= off) ? s[t - off] : 0;
        __syncthreads();
        s[t] += xv;
        __syncthreads();
    }
    if (t < nb) bsum[t] = s[t] - v;   // exclusive
}

__global__ __launch_bounds__(256) void scan3_kernel(
    const int* __restrict__ part, const int* __restrict__ bsum,
    const int* __restrict__ deg, int* __restrict__ rowptr,
    int* __restrict__ bcursor, float* __restrict__ degf, int n, int E)
{
    int i = blockIdx.x * 256 + threadIdx.x;
    if (i == 0) rowptr[n] = E;
    if (i >= n) return;
    int r = part[i] + bsum[i >> 10];
    rowptr[i] = r;
    if ((i & 1023) == 0) bcursor[i >> 10] = r;   // bucket segment base
    degf[i]   = (float)deg[i];
}

// ---------------------------------------------------------------------------
// bin_kernel: LDS multi-split of edges into 196 contiguous-dst buckets.
// ---------------------------------------------------------------------------
__global__ __launch_bounds__(256) void bin_kernel(
    const int* __restrict__ ei, int* __restrict__ bcursor,
    unsigned* __restrict__ binned, int E)
{
    __shared__ int lcnt[256];
    __shared__ int lbase[256];
    __shared__ int gbase[256];
    __shared__ int sc[256];
    __shared__ unsigned stage[4096];
    __shared__ unsigned char stgb[4096];
    const int tid  = threadIdx.x;
    const int base = blockIdx.x * 4096;
    lcnt[tid] = 0;
    __syncthreads();

    unsigned val[16]; short lp[16]; unsigned char bk[16];
#pragma unroll
    for (int i = 0; i < 16; ++i) {
        int e = base + i * 256 + tid;
        if (e < E) {
            int s = ei[e], d = ei[E + e];
            int b = d >> 10;
            val[i] = ((unsigned)s << 10) | (unsigned)(d & 1023);
            bk[i]  = (unsigned char)b;
            lp[i]  = (short)atomicAdd(&lcnt[b], 1);
        } else lp[i] = -1;
    }
    __syncthreads();

    // exclusive scan of per-bucket counts + global range reservation
    int c = lcnt[tid];
    sc[tid] = c;
    __syncthreads();
    for (int off = 1; off < 256; off <<= 1) {
        int v = (tid >= off) ? sc[tid - off] : 0;
        __syncthreads();
        sc[tid] += v;
        __syncthreads();
    }
    lbase[tid] = sc[tid] - c;
    if (c) gbase[tid] = atomicAdd(&bcursor[tid], c);
    __syncthreads();
    const int total = sc[255];

    // bucket-sorted stage in LDS
#pragma unroll
    for (int i = 0; i < 16; ++i) {
        if (lp[i] >= 0) {
            int p = lbase[bk[i]] + lp[i];
            stage[p] = val[i];
            stgb[p]  = bk[i];
        }
    }
    __syncthreads();

    // write out: consecutive p within a bucket -> consecutive global addrs
    for (int p = tid; p < total; p += 256) {
        int b = stgb[p];
        binned[gbase[b] + (p - lbase[b])] = stage[p];
    }
}

// ---------------------------------------------------------------------------
// scatter_kernel: one block per bucket; LDS cursors; writes stay in-bucket.
// ---------------------------------------------------------------------------
__global__ __launch_bounds__(256) void scatter_kernel(
    const unsigned* __restrict__ binned, const int* __restrict__ rowptr,
    int* __restrict__ ssrc)
{
    __shared__ int cur[1024];
    const int b    = blockIdx.x;
    const int tid  = threadIdx.x;
    const int dbase = b << 10;
    const int dmax  = min(1024, N_NODES - dbase);
    for (int j = tid; j < dmax; j += 256) cur[j] = rowptr[dbase + j];
    __syncthreads();
    const int s0 = rowptr[dbase];
    const int s1 = rowptr[dbase + dmax];
    for (int e = s0 + tid; e < s1; e += 256) {
        unsigned v = binned[e];
        int pos = atomicAdd(&cur[v & 1023u], 1);
        ssrc[pos] = (int)(v >> 10);
    }
}

// ---------------------------------------------------------------------------
// Fused SAGE layer (R8): gather via global_load_lds DMA staging.
// R7 post-mortem: compiler pins VGPR=64 and serializes register-staged
// gather loads (2-4 x 256B in flight/wave -> Little's law gives the
// observed 2.3 TB/s wall). global_load_lds needs ZERO VGPRs per
// outstanding load: per pass each wave issues 8 DMA instructions (each =
// 64 lanes x 16B = 1KB = 4 neighbor rows), 8KB in flight per wave, then
// one vmcnt(0) + stride-1 ds_read_b128 accumulate (conflict-free: 64
// lanes cover the 1KB exactly). Tail (deg>8) keeps the register path.
// sched_barrier(0) at pass top stops cross-pass DMA/ds_read reordering
// (the DMA writes alias the stage the previous pass is still reading).
// ---------------------------------------------------------------------------
template<int K, bool L2>
__global__ __launch_bounds__(256, 4) void fused_sage_kernel(
    const float* __restrict__ xgF,           // L1: x (f32 gather src + root)
    const unsigned short* __restrict__ xgB,  // L2: t1 (bf16 gather src + root)
    const int* __restrict__ rowptr, const int* __restrict__ ssrc,
    const bf16x8* __restrict__ Wlp, const bf16x8* __restrict__ Wrp,
    const float* __restrict__ bias,
    const float* __restrict__ c2, const float* __restrict__ degf,
    float* __restrict__ outF, unsigned short* __restrict__ outB,
    float* __restrict__ gsum, float* __restrict__ gsq)
{
    constexpr int KT = K / 32;
    constexpr int RB = K * 2 + 16;            // padded LDS row stride (bytes)
    __shared__ unsigned char sA[FROWS * RB];
    __shared__ unsigned char sStage[4 * 8192];  // 8KB DMA stage per wave
    __shared__ float sS[128];
    __shared__ float sQ[128];

    const int tid  = threadIdx.x;
    const int lane = tid & 63;
    const int wv   = tid >> 6;
    const int m    = lane & 15;
    const int quad = lane >> 4;
    const int li   = lane & 15;
    const int sub  = lane >> 4;               // 0..3 (4 rows per gather pass)
    const int rowbase = blockIdx.x * FROWS + wv * 16;   // wave's 16 rows
    unsigned char* stW = sStage + wv * 8192;  // wave-private stage

    if (tid < 128) { sS[tid] = 0.f; sQ[tid] = 0.f; }

    // ---- root-X prefetch: issued first, drains with the first pass wait ----
    const int rr0 = rowbase + m;
    bf16x8 xReg[KT];
    float4 xr[KT][2];
    if constexpr (L2) {
        const unsigned short* xp = xgB + (size_t)rr0 * K + quad * 8;
#pragma unroll
        for (int kt = 0; kt < KT; ++kt)
            xReg[kt] = *(const bf16x8*)(xp + kt * 32);
    } else {
        const float* xp = xgF + (size_t)rr0 * K + quad * 8;
#pragma unroll
        for (int kt = 0; kt < KT; ++kt) {
            xr[kt][0] = *(const float4*)(xp + kt * 32);
            xr[kt][1] = *(const float4*)(xp + kt * 32 + 4);
        }
    }

    // ---- rowptr for the wave's 16 rows: one coalesced load + shfl ----
    int rpv = rowptr[rowbase + min(lane, 16)];
    int bA[4], eA[4];
#pragma unroll
    for (int g = 0; g < 4; ++g) {
        bA[g] = __shfl(rpv, g * 4 + sub);
        eA[g] = __shfl(rpv, g * 4 + sub + 1);
    }

    // idx loader: q-th neighbor of row (g*4+sub); uniform in 16-lane group
    auto loadIdx = [&](int g, int (&dst)[8]) {
#pragma unroll
        for (int q = 0; q < 8; ++q)
            dst[q] = (bA[g] + q < eA[g]) ? ssrc[bA[g] + q] : 0;
    };

    int idxC[8], idxN[8];
    loadIdx(0, idxC);

    // ---- gather: 4 passes, DMA-staged 8 rows deep ----
    for (int g = 0; g < 4; ++g) {
        __builtin_amdgcn_sched_barrier(0);   // fence prior pass's ds_reads
        const int b = bA[g], e = eA[g];
        const int lrow = wv * 16 + g * 4 + sub;

        // issue 8 DMAs: instr q pulls neighbor q of all 4 rows (1KB)
#pragma unroll
        for (int q = 0; q < 8; ++q) {
            if constexpr (L2)
                gload_lds16(xgB + (size_t)idxC[q] * K + li * 8, stW + q * 1024);
            else
                gload_lds16(xgF + (size_t)idxC[q] * K + li * 4, stW + q * 1024);
        }
        if (g < 3) loadIdx(g + 1, idxN);     // overlaps the DMA wait
        asm volatile("s_waitcnt vmcnt(0)" ::: "memory");

        if constexpr (L2) {
            float acc[8] = {};
#pragma unroll
            for (int q = 0; q < 8; ++q) {
                bf16x8 v = *(const bf16x8*)(stW + q * 1024 + lane * 16);
                float w = (b + q < e) ? 1.f : 0.f;
#pragma unroll
                for (int k = 0; k < 8; ++k)
                    acc[k] = fmaf(bf2f((unsigned short)v[k]), w, acc[k]);
            }
            if (e > b + 8) {   // tail: deg > 8, register path
                int s2[8];
#pragma unroll
                for (int q = 0; q < 8; ++q) s2[q] = (b + 8 + q < e) ? ssrc[b + 8 + q] : 0;
                for (int j = b + 8; j < e; j += 8) {
                    int nn[8];
                    const int jn = j + 8;
#pragma unroll
                    for (int q = 0; q < 8; ++q) nn[q] = (jn + q < e) ? ssrc[jn + q] : 0;
                    bf16x8 v2[8];
#pragma unroll
                    for (int q = 0; q < 8; ++q)
                        v2[q] = *(const bf16x8*)(xgB + (size_t)s2[q] * K + li * 8);
#pragma unroll
                    for (int q = 0; q < 8; ++q) {
                        float w = (j + q < e) ? 1.f : 0.f;
#pragma unroll
                        for (int k = 0; k < 8; ++k)
                            acc[k] = fmaf(bf2f((unsigned short)v2[q][k]), w, acc[k]);
                    }
#pragma unroll
                    for (int q = 0; q < 8; ++q) s2[q] = nn[q];
                }
            }
            bf16x8 o;
#pragma unroll
            for (int k = 0; k < 8; ++k) o[k] = (short)f2bf(acc[k]);
            *(bf16x8*)(sA + lrow * RB + li * 16) = o;
        } else {
            float4 a4 = {0.f, 0.f, 0.f, 0.f};
#pragma unroll
            for (int q = 0; q < 8; ++q) {
                float4 v = *(const float4*)(stW + q * 1024 + lane * 16);
                float w = (b + q < e) ? 1.f : 0.f;
                a4.x = fmaf(v.x, w, a4.x);
                a4.y = fmaf(v.y, w, a4.y);
                a4.z = fmaf(v.z, w, a4.z);
                a4.w = fmaf(v.w, w, a4.w);
            }
            if (e > b + 8) {
                int s2[8];
#pragma unroll
                for (int q = 0; q < 8; ++q) s2[q] = (b + 8 + q < e) ? ssrc[b + 8 + q] : 0;
                for (int j = b + 8; j < e; j += 8) {
                    int nn[8];
                    const int jn = j + 8;
#pragma unroll
                    for (int q = 0; q < 8; ++q) nn[q] = (jn + q < e) ? ssrc[jn + q] : 0;
                    float4 v2[8];
#pragma unroll
                    for (int q = 0; q < 8; ++q)
                        v2[q] = ((const float4*)(xgF + (size_t)s2[q] * K))[li];
#pragma unroll
                    for (int q = 0; q < 8; ++q) {
                        float w = (j + q < e) ? 1.f : 0.f;
                        a4.x = fmaf(v2[q].x, w, a4.x);
                        a4.y = fmaf(v2[q].y, w, a4.y);
                        a4.z = fmaf(v2[q].z, w, a4.z);
                        a4.w = fmaf(v2[q].w, w, a4.w);
                    }
#pragma unroll
                    for (int q = 0; q < 8; ++q) s2[q] = nn[q];
                }
            }
            us4 o;
            o.x = f2bf(a4.x); o.y = f2bf(a4.y); o.z = f2bf(a4.z); o.w = f2bf(a4.w);
            *(us4*)(sA + lrow * RB + li * 8) = o;
        }
#pragma unroll
        for (int q = 0; q < 8; ++q) idxC[q] = idxN[q];
    }

    // L1: convert prefetched f32 root row to bf16 fragments
    if constexpr (!L2) {
#pragma unroll
        for (int kt = 0; kt < KT; ++kt) {
            xReg[kt][0] = (short)f2bf(xr[kt][0].x);
            xReg[kt][1] = (short)f2bf(xr[kt][0].y);
            xReg[kt][2] = (short)f2bf(xr[kt][0].z);
            xReg[kt][3] = (short)f2bf(xr[kt][0].w);
            xReg[kt][4] = (short)f2bf(xr[kt][1].x);
            xReg[kt][5] = (short)f2bf(xr[kt][1].y);
            xReg[kt][6] = (short)f2bf(xr[kt][1].z);
            xReg[kt][7] = (short)f2bf(xr[kt][1].w);
        }
    }

    // per-nt epilogue constants (col = nt*16 + m)
    float bcol[8], ccol[8];
#pragma unroll
    for (int nt = 0; nt < 8; ++nt) {
        bcol[nt] = bias[nt * 16 + m];
        if constexpr (L2) ccol[nt] = c2[nt * 16 + m];
    }

    __syncthreads();   // A-tile complete (also covers sS/sQ init)

    // ---- A fragments from LDS (padded stride: conflict-free) ----
    bf16x8 aReg[KT];
    {
        const unsigned char* ap = sA + (wv * 16 + m) * RB + quad * 16;
#pragma unroll
        for (int kt = 0; kt < KT; ++kt)
            aReg[kt] = *(const bf16x8*)(ap + kt * 64);
    }

    // ---- K loop: weights from global (L2-hot) + MFMA ----
    f32x4 acc[8] = {};
#pragma unroll
    for (int kt = 0; kt < KT; ++kt) {
#pragma unroll
        for (int nt = 0; nt < 8; ++nt) {
            bf16x8 wl = Wlp[(nt * KT + kt) * 64 + lane];
            acc[nt] = __builtin_amdgcn_mfma_f32_16x16x32_bf16(
                aReg[kt], wl, acc[nt], 0, 0, 0);
            bf16x8 wr = Wrp[(nt * KT + kt) * 64 + lane];
            acc[nt] = __builtin_amdgcn_mfma_f32_16x16x32_bf16(
                xReg[kt], wr, acc[nt], 0, 0, 0);
        }
    }

    // ---- epilogue: C/D layout col = lane&15, row = quad*4 + reg ----
    float stS[8] = {}, stQ[8] = {};
    const int orow = rowbase + quad * 4;
    float dg[4];
    if constexpr (L2) {
#pragma unroll
        for (int r = 0; r < 4; ++r) dg[r] = degf[orow + r];
    }
#pragma unroll
    for (int nt = 0; nt < 8; ++nt) {
        int col = nt * 16 + m;
#pragma unroll
        for (int r = 0; r < 4; ++r) {
            float base = L2 ? fmaf(dg[r], ccol[nt], bcol[nt]) : bcol[nt];
            float v = fmaxf(acc[nt][r] + base, 0.f);
            if constexpr (L2) outF[(size_t)(orow + r) * 128 + col] = v;
            else              outB[(size_t)(orow + r) * 128 + col] = f2bf(v);
            stS[nt] += v;
            stQ[nt] = fmaf(v, v, stQ[nt]);
        }
    }

    // ---- stats reduce: registers -> LDS -> global replica (8 replicas) ----
#pragma unroll
    for (int nt = 0; nt < 8; ++nt) {
        atomicAdd(&sS[nt * 16 + m], stS[nt]);
        atomicAdd(&sQ[nt * 16 + m], stQ[nt]);
    }
    __syncthreads();
    const int rep = (blockIdx.x & 7) * 128;
    if (tid < 128) {
        atomicAdd(&gsum[rep + tid], sS[tid]);
        atomicAdd(&gsq[rep + tid],  sQ[tid]);
    }
}

// ---------------------------------------------------------------------------
// BN finalize: per-feature scale/shift (sums the 8 stats replicas).
// ---------------------------------------------------------------------------
__global__ void bn_finalize_kernel(
    const float* __restrict__ gsum, const float* __restrict__ gsq,
    const float* __restrict__ g, const float* __restrict__ be,
    float* __restrict__ scale, float* __restrict__ shift, float invN)
{
    int c = threadIdx.x;  // 128
    float s = 0.f, q = 0.f;
#pragma unroll
    for (int k = 0; k < 8; ++k) {
        s += gsum[k * 128 + c];
        q += gsq[k * 128 + c];
    }
    float mean = s * invN;
    float var  = fmaxf(q * invN - mean * mean, 0.f);
    float sc   = g[c] * rsqrtf(var + BN_EPS);
    scale[c] = sc;
    shift[c] = be[c] - mean * sc;
}

// BN1 fold constants: c2 = shift1@W2l ; crb = shift1@W2r + b2
__global__ void bn_fold_kernel(
    const float* __restrict__ shift1, const float* __restrict__ W2l,
    const float* __restrict__ W2r, const float* __restrict__ b2,
    float* __restrict__ c2, float* __restrict__ crb)
{
    int col = threadIdx.x;  // 128
    float a = 0.f, r = 0.f;
    for (int k = 0; k < 128; ++k) {
        float s = shift1[k];
        a = fmaf(s, W2l[(size_t)k * 128 + col], a);
        r = fmaf(s, W2r[(size_t)k * 128 + col], r);
    }
    c2[col]  = a;
    crb[col] = r + b2[col];
}

// ---------------------------------------------------------------------------
// Final BN apply + ReLU (in place on d_out).
// ---------------------------------------------------------------------------
__global__ __launch_bounds__(256) void bn_apply_relu_kernel(
    float* __restrict__ h, const float* __restrict__ scale,
    const float* __restrict__ shift, int n4)
{
    int i = blockIdx.x * 256 + threadIdx.x;
    if (i >= n4) return;
    int cb = i & 31;
    float4 v  = ((float4*)h)[i];
    float4 sc = ((const float4*)scale)[cb];
    float4 sh = ((const float4*)shift)[cb];
    v.x = fmaxf(fmaf(v.x, sc.x, sh.x), 0.f);
    v.y = fmaxf(fmaf(v.y, sc.y, sh.y), 0.f);
    v.z = fmaxf(fmaf(v.z, sc.z, sh.z), 0.f);
    v.w = fmaxf(fmaf(v.w, sc.w, sh.w), 0.f);
    ((float4*)h)[i] = v;
}

extern "C" void kernel_launch(void* const* d_in, const int* in_sizes, int n_in,
                              void* d_out, int out_size, void* d_ws, size_t ws_size,
                              hipStream_t stream) {
    const float* x   = (const float*)d_in[0];
    const int*   ei  = (const int*)d_in[1];
    const float* W1l = (const float*)d_in[2];
    const float* b1  = (const float*)d_in[3];
    const float* W1r = (const float*)d_in[4];
    const float* g1  = (const float*)d_in[5];
    const float* be1 = (const float*)d_in[6];
    const float* W2l = (const float*)d_in[7];
    const float* b2  = (const float*)d_in[8];
    const float* W2r = (const float*)d_in[9];
    const float* g2  = (const float*)d_in[10];
    const float* be2 = (const float*)d_in[11];
    float* out = (float*)d_out;

    const int N = N_NODES, E = N_EDGES;
    const int NB1 = (N + 1023) / 1024;          // 196 scan blocks
    const int nT  = N / FROWS;                  // 3125 fused blocks

    // Workspace layout (float units):
    float* ws     = (float*)d_ws;
    float* gsum1  = ws;          float* gsq1   = ws + 1024;   // 8 replicas x 128
    float* gsum2  = ws + 2048;   float* gsq2   = ws + 3072;
    float* scale1 = ws + 4096;   float* shift1 = ws + 4224;
    float* scale2 = ws + 4352;   float* shift2 = ws + 4480;
    float* c2v    = ws + 4608;   float* crb    = ws + 4736;
    short* W1lp = (short*)(ws + 5120);                        // 4096 f
    short* W1rp = (short*)(ws + 5120 + 4096);                 // 4096 f
    short* W2lp = (short*)(ws + 5120 + 8192);                 // 8192 f
    short* W2rp = (short*)(ws + 5120 + 16384);                // 8192 f
    int*   deg    = (int*)(ws + 29696);                       // N
    int*   part   = deg + N;                                  // N
    int*   bsum   = part + N;                                 // 1024
    int*   rowptr = bsum + 1024;                              // N+1 (pad 1024)
    int*   bcursor= rowptr + (N + 1024);                      // 256
    float* degf   = (float*)(bcursor + 256);                  // N
    int*   ssrc   = (int*)(degf + N);                         // E
    unsigned short* t1   = (unsigned short*)(ssrc + E);       // N*128 bf16
    unsigned* binned = (unsigned*)(t1 + (size_t)N * F_H);     // E u32

    // ---- Graph build + layer-1 weight pack ----
    hipMemsetAsync(ws, 0, 4096 * sizeof(float), stream);      // stats replicas
    hipMemsetAsync(deg, 0, (size_t)N * sizeof(int), stream);
    pack_weights_kernel<<<4, 256, 0, stream>>>(W1l, nullptr, W1lp, 2);
    pack_weights_kernel<<<4, 256, 0, stream>>>(W1r, nullptr, W1rp, 2);
    hist_kernel<<<(E + 255) / 256, 256, 0, stream>>>(ei, deg, E);
    scan1_kernel<<<NB1, 256, 0, stream>>>(deg, part, bsum, N);
    scan2_kernel<<<1, 256, 0, stream>>>(bsum, NB1);
    scan3_kernel<<<(N + 255) / 256, 256, 0, stream>>>(part, bsum, deg, rowptr,
                                                      bcursor, degf, N, E);
    bin_kernel<<<BINB, 256, 0, stream>>>(ei, bcursor, binned, E);
    scatter_kernel<<<NBUK, 256, 0, stream>>>(binned, rowptr, ssrc);

    // ---- Layer 1 (fused gather + GEMM + stats) ----
    fused_sage_kernel<F_IN, false><<<nT, 256, 0, stream>>>(
        x, nullptr, rowptr, ssrc,
        (const bf16x8*)W1lp, (const bf16x8*)W1rp, b1,
        nullptr, nullptr, nullptr, t1, gsum1, gsq1);
    bn_finalize_kernel<<<1, 128, 0, stream>>>(gsum1, gsq1, g1, be1,
                                              scale1, shift1, 1.f / N);

    // ---- Layer 2 (BN1 folded: scale1 into weights, shift1 into c2/crb) ----
    pack_weights_kernel<<<8, 256, 0, stream>>>(W2l, scale1, W2lp, 4);
    pack_weights_kernel<<<8, 256, 0, stream>>>(W2r, scale1, W2rp, 4);
    bn_fold_kernel<<<1, 128, 0, stream>>>(shift1, W2l, W2r, b2, c2v, crb);
    fused_sage_kernel<F_H, true><<<nT, 256, 0, stream>>>(
        nullptr, t1, rowptr, ssrc,
        (const bf16x8*)W2lp, (const bf16x8*)W2rp, crb,
        c2v, degf, out, nullptr, gsum2, gsq2);
    bn_finalize_kernel<<<1, 128, 0, stream>>>(gsum2, gsq2, g2, be2,
                                              scale2, shift2, 1.f / N);
    bn_apply_relu_kernel<<<(N * F_H / 4 + 255) / 256, 256, 0, stream>>>(
        out, scale2, shift2, N * F_H / 4);
}

// Round 11
// 517.322 us; speedup vs baseline: 1.1450x; 1.1450x over previous
//
#include <hip/hip_runtime.h>

#define N_NODES 200000
#define N_EDGES 1200000
#define F_IN    64
#define F_H     128
#define BN_EPS  1e-5f
#define NBUK    196          // ceil(N/1024) dst-buckets of 1024 nodes
#define BINB    293          // ceil(E/4096) bin blocks

typedef short bf16x8 __attribute__((ext_vector_type(8)));   // 8 bf16 in 4 VGPRs
typedef float f32x4  __attribute__((ext_vector_type(4)));
typedef unsigned short us4 __attribute__((ext_vector_type(4)));

__device__ __forceinline__ unsigned short f2bf(float f) {
    union { float f; unsigned u; } v; v.f = f;
    unsigned r = (v.u + 0x7FFFu + ((v.u >> 16) & 1u)) >> 16;  // RNE
    return (unsigned short)r;
}
__device__ __forceinline__ float bf2f(unsigned short b) {
    union { unsigned u; float f; } v; v.u = ((unsigned)b) << 16;
    return v.f;
}

// per-lane gather slice type: 16 lanes cover one K-row (K*2 bytes)
template<int K> struct ldsel       { using T = bf16x8; };  // K=128: 16B/lane
template<>      struct ldsel<64>   { using T = us4;    };  // K=64 :  8B/lane

// ---------------------------------------------------------------------------
// x -> bf16 convert (R11): halves the bytes the L1 random gather must move.
// ---------------------------------------------------------------------------
__global__ __launch_bounds__(256) void cvt_bf16_kernel(
    const float* __restrict__ x, unsigned short* __restrict__ xb, int n8)
{
    int i = blockIdx.x * 256 + threadIdx.x;
    if (i >= n8) return;
    float4 a = ((const float4*)x)[i * 2];
    float4 b = ((const float4*)x)[i * 2 + 1];
    bf16x8 o;
    o[0] = (short)f2bf(a.x); o[1] = (short)f2bf(a.y);
    o[2] = (short)f2bf(a.z); o[3] = (short)f2bf(a.w);
    o[4] = (short)f2bf(b.x); o[5] = (short)f2bf(b.y);
    o[6] = (short)f2bf(b.z); o[7] = (short)f2bf(b.w);
    ((bf16x8*)xb)[i] = o;
}

// ---------------------------------------------------------------------------
// Weight pack into bf16 MFMA B-fragment order for mfma_f32_16x16x32_bf16.
// ---------------------------------------------------------------------------
__global__ void pack_weights_kernel(const float* __restrict__ W,
                                    const float* __restrict__ kscale,
                                    short* __restrict__ P, int KT)
{
    int t = blockIdx.x * 256 + threadIdx.x;            // over 8*KT*64
    if (t >= 8 * KT * 64) return;
    int lane = t & 63;
    int kt   = (t >> 6) % KT;
    int nt   = t / (64 * KT);
    int k0   = kt * 32 + (lane >> 4) * 8;
    int n    = nt * 16 + (lane & 15);
#pragma unroll
    for (int j = 0; j < 8; ++j) {
        float w = W[(size_t)(k0 + j) * 128 + n];
        if (kscale) w *= kscale[k0 + j];
        P[(size_t)t * 8 + j] = (short)f2bf(w);
    }
}

// ---------------------------------------------------------------------------
// CSR build: histogram -> 2-level exclusive scan over deg -> bucketed fill
// ---------------------------------------------------------------------------
__global__ __launch_bounds__(256) void hist_kernel(const int* __restrict__ ei,
                                                   int* __restrict__ deg, int E)
{
    int e = blockIdx.x * 256 + threadIdx.x;
    if (e < E) atomicAdd(&deg[ei[E + e]], 1);
}

__global__ __launch_bounds__(256) void scan1_kernel(const int* __restrict__ deg,
        int* __restrict__ part, int* __restrict__ bsum, int n)
{
    __shared__ int s[256];
    int t = threadIdx.x;
    int base = blockIdx.x * 1024 + t * 4;
    int v[4];
#pragma unroll
    for (int j = 0; j < 4; ++j) v[j] = (base + j < n) ? deg[base + j] : 0;
    int tsum = v[0] + v[1] + v[2] + v[3];
    s[t] = tsum;
    __syncthreads();
    for (int off = 1; off < 256; off <<= 1) {
        int xv = (t >= off) ? s[t - off] : 0;
        __syncthreads();
        s[t] += xv;
        __syncthreads();
    }
    int excl = s[t] - tsum;
#pragma unroll
    for (int j = 0; j < 4; ++j) {
        if (base + j < n) part[base + j] = excl;
        excl += v[j];
    }
    if (t == 255) bsum[blockIdx.x] = s[255];
}

__global__ void scan2_kernel(int* __restrict__ bsum, int nb)
{
    __shared__ int s[256];
    int t = threadIdx.x;
    int v = (t < nb) ? bsum[t] : 0;
    s[t] = v;
    __syncthreads();
    for (int off = 1; off < 256; off <<= 1) {
        int xv = (t >= off) ? s[t - off] : 0;
        __syncthreads();
        s[t] += xv;
        __syncthreads();
    }
    if (t < nb) bsum[t] = s[t] - v;   // exclusive
}

__global__ __launch_bounds__(256) void scan3_kernel(
    const int* __restrict__ part, const int* __restrict__ bsum,
    const int* __restrict__ deg, int* __restrict__ rowptr,
    int* __restrict__ bcursor, float* __restrict__ degf, int n, int E)
{
    int i = blockIdx.x * 256 + threadIdx.x;
    if (i == 0) rowptr[n] = E;
    if (i >= n) return;
    int r = part[i] + bsum[i >> 10];
    rowptr[i] = r;
    if ((i & 1023) == 0) bcursor[i >> 10] = r;   // bucket segment base
    degf[i]   = (float)deg[i];
}

// ---------------------------------------------------------------------------
// bin_kernel: LDS multi-split of edges into 196 contiguous-dst buckets.
// ---------------------------------------------------------------------------
__global__ __launch_bounds__(256) void bin_kernel(
    const int* __restrict__ ei, int* __restrict__ bcursor,
    unsigned* __restrict__ binned, int E)
{
    __shared__ int lcnt[256];
    __shared__ int lbase[256];
    __shared__ int gbase[256];
    __shared__ int sc[256];
    __shared__ unsigned stage[4096];
    __shared__ unsigned char stgb[4096];
    const int tid  = threadIdx.x;
    const int base = blockIdx.x * 4096;
    lcnt[tid] = 0;
    __syncthreads();

    unsigned val[16]; short lp[16]; unsigned char bk[16];
#pragma unroll
    for (int i = 0; i < 16; ++i) {
        int e = base + i * 256 + tid;
        if (e < E) {
            int s = ei[e], d = ei[E + e];
            int b = d >> 10;
            val[i] = ((unsigned)s << 10) | (unsigned)(d & 1023);
            bk[i]  = (unsigned char)b;
            lp[i]  = (short)atomicAdd(&lcnt[b], 1);
        } else lp[i] = -1;
    }
    __syncthreads();

    // exclusive scan of per-bucket counts + global range reservation
    int c = lcnt[tid];
    sc[tid] = c;
    __syncthreads();
    for (int off = 1; off < 256; off <<= 1) {
        int v = (tid >= off) ? sc[tid - off] : 0;
        __syncthreads();
        sc[tid] += v;
        __syncthreads();
    }
    lbase[tid] = sc[tid] - c;
    if (c) gbase[tid] = atomicAdd(&bcursor[tid], c);
    __syncthreads();
    const int total = sc[255];

    // bucket-sorted stage in LDS
#pragma unroll
    for (int i = 0; i < 16; ++i) {
        if (lp[i] >= 0) {
            int p = lbase[bk[i]] + lp[i];
            stage[p] = val[i];
            stgb[p]  = bk[i];
        }
    }
    __syncthreads();

    // write out: consecutive p within a bucket -> consecutive global addrs
    for (int p = tid; p < total; p += 256) {
        int b = stgb[p];
        binned[gbase[b] + (p - lbase[b])] = stage[p];
    }
}

// ---------------------------------------------------------------------------
// scatter_kernel: one block per bucket; LDS cursors; writes stay in-bucket.
// ---------------------------------------------------------------------------
__global__ __launch_bounds__(256) void scatter_kernel(
    const unsigned* __restrict__ binned, const int* __restrict__ rowptr,
    int* __restrict__ ssrc)
{
    __shared__ int cur[1024];
    const int b    = blockIdx.x;
    const int tid  = threadIdx.x;
    const int dbase = b << 10;
    const int dmax  = min(1024, N_NODES - dbase);
    for (int j = tid; j < dmax; j += 256) cur[j] = rowptr[dbase + j];
    __syncthreads();
    const int s0 = rowptr[dbase];
    const int s1 = rowptr[dbase + dmax];
    for (int e = s0 + tid; e < s1; e += 256) {
        unsigned v = binned[e];
        int pos = atomicAdd(&cur[v & 1023u], 1);
        ssrc[pos] = (int)(v >> 10);
    }
}

// ---------------------------------------------------------------------------
// Fused SAGE layer (R11 = R5 structure, unified bf16 gather).
// R5 geometry (best passing: 128-row blocks, 32 rows/wave, 2-stage index
// pipeline) with BOTH layers gathering bf16 rows: L1 from pre-converted
// xb (128B/row instead of 256B f32 — halves the random-gather traffic),
// L2 from t1 as before. Per-lane slice: K=64 -> 8B (us4), K=128 -> 16B
// (bf16x8). R7-R10's forced-MLP mechanisms are abandoned (RA-unsafe /
// racy); this is the traffic-side lever instead.
// ---------------------------------------------------------------------------
template<int K, bool L2>
__global__ __launch_bounds__(256, 2) void fused_sage_kernel(
    const unsigned short* __restrict__ xgB,  // bf16 gather src + root rows
    const int* __restrict__ rowptr, const int* __restrict__ ssrc,
    const bf16x8* __restrict__ Wlp, const bf16x8* __restrict__ Wrp,
    const float* __restrict__ bias,
    const float* __restrict__ c2, const float* __restrict__ degf,
    float* __restrict__ outF, unsigned short* __restrict__ outB,
    float* __restrict__ gsum, float* __restrict__ gsq)
{
    constexpr int KT = K / 32;
    constexpr int NA = K / 16;                // bf16 elems per lane slice
    constexpr int RB = K * 2 + 16;            // padded LDS row stride (bytes)
    using ldT = typename ldsel<K>::T;
    __shared__ unsigned char sA[128 * RB];
    __shared__ float sS[128];
    __shared__ float sQ[128];

    const int tid  = threadIdx.x;
    const int lane = tid & 63;
    const int wv   = tid >> 6;
    const int m    = lane & 15;
    const int quad = lane >> 4;
    const int li   = lane & 15;
    const int sub  = lane >> 4;               // 0..3 (4 rows per gather pass)
    const int rowbase = blockIdx.x * 128 + wv * 32;

    if (tid < 128) { sS[tid] = 0.f; sQ[tid] = 0.f; }

    // ---- root-X prefetch: issued first, lands during the gather phase ----
    int rc[2];
#pragma unroll
    for (int st = 0; st < 2; ++st) {
        int r = rowbase + st * 16 + m;
        rc[st] = r < N_NODES ? r : N_NODES - 1;
    }
    bf16x8 xReg[2][KT];
#pragma unroll
    for (int st = 0; st < 2; ++st) {
        const unsigned short* xp = xgB + (size_t)rc[st] * K + quad * 8;
#pragma unroll
        for (int kt = 0; kt < KT; ++kt)
            xReg[st][kt] = *(const bf16x8*)(xp + kt * 32);
    }

    // ---- rowptr for the wave's 32 rows: one coalesced load + shfl ----
    int rpv = rowptr[min(rowbase + min(lane, 32), N_NODES)];
    int bA[8], eA[8];
#pragma unroll
    for (int g = 0; g < 8; ++g) {
        bA[g] = __shfl(rpv, g * 4 + sub);
        eA[g] = __shfl(rpv, g * 4 + sub + 1);
    }

    auto loadRow = [&](int idx) -> ldT {
        if constexpr (K == 128)
            return *(const bf16x8*)(xgB + (size_t)idx * K + li * 8);
        else
            return *(const us4*)(xgB + (size_t)idx * K + li * 4);
    };

    // ---- gather phase: 8 passes, indices prefetched one pass ahead ----
    int sN[8];
#pragma unroll
    for (int q = 0; q < 8; ++q) sN[q] = (bA[0] + q < eA[0]) ? ssrc[bA[0] + q] : 0;

    for (int g = 0; g < 8; ++g) {
        const int lrow = wv * 32 + g * 4 + sub;
        const int b = bA[g], e = eA[g];
        int sC[8];
#pragma unroll
        for (int q = 0; q < 8; ++q) sC[q] = sN[q];

        // issue this pass's feature loads
        ldT v[8];
#pragma unroll
        for (int q = 0; q < 8; ++q) v[q] = loadRow(sC[q]);
        // prefetch next pass's indices (independent — overlaps v)
        if (g < 7) {
#pragma unroll
            for (int q = 0; q < 8; ++q)
                sN[q] = (bA[g+1] + q < eA[g+1]) ? ssrc[bA[g+1] + q] : 0;
        }
        float acc[NA] = {};
#pragma unroll
        for (int q = 0; q < 8; ++q) {
            float w = (b + q < e) ? 1.f : 0.f;
#pragma unroll
            for (int k = 0; k < NA; ++k)
                acc[k] = fmaf(bf2f((unsigned short)v[q][k]), w, acc[k]);
        }
        // tail: deg > 8 (batched, as before)
        if (e > b + 8) {
            int s2[8];
#pragma unroll
            for (int q = 0; q < 8; ++q) s2[q] = (b + 8 + q < e) ? ssrc[b + 8 + q] : 0;
            for (int j = b + 8; j < e; j += 8) {
                int nn[8];
                const int jn = j + 8;
#pragma unroll
                for (int q = 0; q < 8; ++q) nn[q] = (jn + q < e) ? ssrc[jn + q] : 0;
                ldT v2[8];
#pragma unroll
                for (int q = 0; q < 8; ++q) v2[q] = loadRow(s2[q]);
#pragma unroll
                for (int q = 0; q < 8; ++q) {
                    float w = (j + q < e) ? 1.f : 0.f;
#pragma unroll
                    for (int k = 0; k < NA; ++k)
                        acc[k] = fmaf(bf2f((unsigned short)v2[q][k]), w, acc[k]);
                }
#pragma unroll
                for (int q = 0; q < 8; ++q) s2[q] = nn[q];
            }
        }
        ldT o;
#pragma unroll
        for (int k = 0; k < NA; ++k) o[k] = (short)f2bf(acc[k]);
        *(ldT*)(sA + lrow * RB + li * sizeof(ldT)) = o;
    }

    // per-nt epilogue constants (col = nt*16 + m)
    float bcol[8], ccol[8];
#pragma unroll
    for (int nt = 0; nt < 8; ++nt) {
        bcol[nt] = bias[nt * 16 + m];
        if constexpr (L2) ccol[nt] = c2[nt * 16 + m];
    }

    __syncthreads();   // A-tile complete

    // ---- A fragments from LDS (padded stride: conflict-free) ----
    bf16x8 aReg[2][KT];
#pragma unroll
    for (int st = 0; st < 2; ++st) {
        const unsigned char* ap = sA + (wv * 32 + st * 16 + m) * RB + quad * 16;
#pragma unroll
        for (int kt = 0; kt < KT; ++kt)
            aReg[st][kt] = *(const bf16x8*)(ap + kt * 64);
    }

    // ---- K loop: weights from global (L2-hot) + MFMA ----
    f32x4 acc[2][8] = {};
#pragma unroll
    for (int kt = 0; kt < KT; ++kt) {
#pragma unroll
        for (int nt = 0; nt < 8; ++nt) {
            bf16x8 wl = Wlp[(nt * KT + kt) * 64 + lane];
#pragma unroll
            for (int st = 0; st < 2; ++st)
                acc[st][nt] = __builtin_amdgcn_mfma_f32_16x16x32_bf16(
                    aReg[st][kt], wl, acc[st][nt], 0, 0, 0);
            bf16x8 wr = Wrp[(nt * KT + kt) * 64 + lane];
#pragma unroll
            for (int st = 0; st < 2; ++st)
                acc[st][nt] = __builtin_amdgcn_mfma_f32_16x16x32_bf16(
                    xReg[st][kt], wr, acc[st][nt], 0, 0, 0);
        }
    }

    // ---- epilogue: C/D layout col = lane&15, row = quad*4 + reg ----
    float stS[8] = {}, stQ[8] = {};
#pragma unroll
    for (int st = 0; st < 2; ++st) {
        const int orow = rowbase + st * 16 + quad * 4;
        float dg[4];
        if constexpr (L2) {
#pragma unroll
            for (int r = 0; r < 4; ++r) {
                int rr = orow + r;
                dg[r] = (rr < N_NODES) ? degf[rr] : 0.f;
            }
        }
#pragma unroll
        for (int nt = 0; nt < 8; ++nt) {
            int col = nt * 16 + m;
#pragma unroll
            for (int r = 0; r < 4; ++r) {
                int rr = orow + r;
                if (rr < N_NODES) {
                    float base = L2 ? fmaf(dg[r], ccol[nt], bcol[nt]) : bcol[nt];
                    float v = fmaxf(acc[st][nt][r] + base, 0.f);
                    if constexpr (L2) outF[(size_t)rr * 128 + col] = v;
                    else              outB[(size_t)rr * 128 + col] = f2bf(v);
                    stS[nt] += v;
                    stQ[nt] = fmaf(v, v, stQ[nt]);
                }
            }
        }
    }

    // ---- stats reduce: registers -> LDS -> global replica (8 replicas) ----
#pragma unroll
    for (int nt = 0; nt < 8; ++nt) {
        atomicAdd(&sS[nt * 16 + m], stS[nt]);
        atomicAdd(&sQ[nt * 16 + m], stQ[nt]);
    }
    __syncthreads();
    const int rep = (blockIdx.x & 7) * 128;
    if (tid < 128) {
        atomicAdd(&gsum[rep + tid], sS[tid]);
        atomicAdd(&gsq[rep + tid],  sQ[tid]);
    }
}

// ---------------------------------------------------------------------------
// BN finalize: per-feature scale/shift (sums the 8 stats replicas).
// ---------------------------------------------------------------------------
__global__ void bn_finalize_kernel(
    const float* __restrict__ gsum, const float* __restrict__ gsq,
    const float* __restrict__ g, const float* __restrict__ be,
    float* __restrict__ scale, float* __restrict__ shift, float invN)
{
    int c = threadIdx.x;  // 128
    float s = 0.f, q = 0.f;
#pragma unroll
    for (int k = 0; k < 8; ++k) {
        s += gsum[k * 128 + c];
        q += gsq[k * 128 + c];
    }
    float mean = s * invN;
    float var  = fmaxf(q * invN - mean * mean, 0.f);
    float sc   = g[c] * rsqrtf(var + BN_EPS);
    scale[c] = sc;
    shift[c] = be[c] - mean * sc;
}

// BN1 fold constants: c2 = shift1@W2l ; crb = shift1@W2r + b2
__global__ void bn_fold_kernel(
    const float* __restrict__ shift1, const float* __restrict__ W2l,
    const float* __restrict__ W2r, const float* __restrict__ b2,
    float* __restrict__ c2, float* __restrict__ crb)
{
    int col = threadIdx.x;  // 128
    float a = 0.f, r = 0.f;
    for (int k = 0; k < 128; ++k) {
        float s = shift1[k];
        a = fmaf(s, W2l[(size_t)k * 128 + col], a);
        r = fmaf(s, W2r[(size_t)k * 128 + col], r);
    }
    c2[col]  = a;
    crb[col] = r + b2[col];
}

// ---------------------------------------------------------------------------
// Final BN apply + ReLU (in place on d_out).
// ---------------------------------------------------------------------------
__global__ __launch_bounds__(256) void bn_apply_relu_kernel(
    float* __restrict__ h, const float* __restrict__ scale,
    const float* __restrict__ shift, int n4)
{
    int i = blockIdx.x * 256 + threadIdx.x;
    if (i >= n4) return;
    int cb = i & 31;
    float4 v  = ((float4*)h)[i];
    float4 sc = ((const float4*)scale)[cb];
    float4 sh = ((const float4*)shift)[cb];
    v.x = fmaxf(fmaf(v.x, sc.x, sh.x), 0.f);
    v.y = fmaxf(fmaf(v.y, sc.y, sh.y), 0.f);
    v.z = fmaxf(fmaf(v.z, sc.z, sh.z), 0.f);
    v.w = fmaxf(fmaf(v.w, sc.w, sh.w), 0.f);
    ((float4*)h)[i] = v;
}

extern "C" void kernel_launch(void* const* d_in, const int* in_sizes, int n_in,
                              void* d_out, int out_size, void* d_ws, size_t ws_size,
                              hipStream_t stream) {
    const float* x   = (const float*)d_in[0];
    const int*   ei  = (const int*)d_in[1];
    const float* W1l = (const float*)d_in[2];
    const float* b1  = (const float*)d_in[3];
    const float* W1r = (const float*)d_in[4];
    const float* g1  = (const float*)d_in[5];
    const float* be1 = (const float*)d_in[6];
    const float* W2l = (const float*)d_in[7];
    const float* b2  = (const float*)d_in[8];
    const float* W2r = (const float*)d_in[9];
    const float* g2  = (const float*)d_in[10];
    const float* be2 = (const float*)d_in[11];
    float* out = (float*)d_out;

    const int N = N_NODES, E = N_EDGES;
    const int NB1 = (N + 1023) / 1024;          // 196 scan blocks
    const int nT  = (N + 127) / 128;            // 1563 fused blocks

    // Workspace layout (float units):
    float* ws     = (float*)d_ws;
    float* gsum1  = ws;          float* gsq1   = ws + 1024;   // 8 replicas x 128
    float* gsum2  = ws + 2048;   float* gsq2   = ws + 3072;
    float* scale1 = ws + 4096;   float* shift1 = ws + 4224;
    float* scale2 = ws + 4352;   float* shift2 = ws + 4480;
    float* c2v    = ws + 4608;   float* crb    = ws + 4736;
    short* W1lp = (short*)(ws + 5120);                        // 4096 f
    short* W1rp = (short*)(ws + 5120 + 4096);                 // 4096 f
    short* W2lp = (short*)(ws + 5120 + 8192);                 // 8192 f
    short* W2rp = (short*)(ws + 5120 + 16384);                // 8192 f
    int*   deg    = (int*)(ws + 29696);                       // N
    int*   part   = deg + N;                                  // N
    int*   bsum   = part + N;                                 // 1024
    int*   rowptr = bsum + 1024;                              // N+1 (pad 1024)
    int*   bcursor= rowptr + (N + 1024);                      // 256
    float* degf   = (float*)(bcursor + 256);                  // N
    int*   ssrc   = (int*)(degf + N);                         // E
    unsigned short* t1   = (unsigned short*)(ssrc + E);       // N*128 bf16
    unsigned* binned = (unsigned*)(t1 + (size_t)N * F_H);     // E u32
    unsigned short* xb = (unsigned short*)(binned + E);       // N*64 bf16

    // ---- Graph build + layer-1 weight pack + x->bf16 convert ----
    hipMemsetAsync(ws, 0, 4096 * sizeof(float), stream);      // stats replicas
    hipMemsetAsync(deg, 0, (size_t)N * sizeof(int), stream);
    pack_weights_kernel<<<4, 256, 0, stream>>>(W1l, nullptr, W1lp, 2);
    pack_weights_kernel<<<4, 256, 0, stream>>>(W1r, nullptr, W1rp, 2);
    cvt_bf16_kernel<<<(N * F_IN / 8 + 255) / 256, 256, 0, stream>>>(
        x, xb, N * F_IN / 8);
    hist_kernel<<<(E + 255) / 256, 256, 0, stream>>>(ei, deg, E);
    scan1_kernel<<<NB1, 256, 0, stream>>>(deg, part, bsum, N);
    scan2_kernel<<<1, 256, 0, stream>>>(bsum, NB1);
    scan3_kernel<<<(N + 255) / 256, 256, 0, stream>>>(part, bsum, deg, rowptr,
                                                      bcursor, degf, N, E);
    bin_kernel<<<BINB, 256, 0, stream>>>(ei, bcursor, binned, E);
    scatter_kernel<<<NBUK, 256, 0, stream>>>(binned, rowptr, ssrc);

    // ---- Layer 1 (fused gather + GEMM + stats; bf16 gather from xb) ----
    fused_sage_kernel<F_IN, false><<<nT, 256, 0, stream>>>(
        xb, rowptr, ssrc,
        (const bf16x8*)W1lp, (const bf16x8*)W1rp, b1,
        nullptr, nullptr, nullptr, t1, gsum1, gsq1);
    bn_finalize_kernel<<<1, 128, 0, stream>>>(gsum1, gsq1, g1, be1,
                                              scale1, shift1, 1.f / N);

    // ---- Layer 2 (BN1 folded: scale1 into weights, shift1 into c2/crb) ----
    pack_weights_kernel<<<8, 256, 0, stream>>>(W2l, scale1, W2lp, 4);
    pack_weights_kernel<<<8, 256, 0, stream>>>(W2r, scale1, W2rp, 4);
    bn_fold_kernel<<<1, 128, 0, stream>>>(shift1, W2l, W2r, b2, c2v, crb);
    fused_sage_kernel<F_H, true><<<nT, 256, 0, stream>>>(
        t1, rowptr, ssrc,
        (const bf16x8*)W2lp, (const bf16x8*)W2rp, crb,
        c2v, degf, out, nullptr, gsum2, gsq2);
    bn_finalize_kernel<<<1, 128, 0, stream>>>(gsum2, gsq2, g2, be2,
                                              scale2, shift2, 1.f / N);
    bn_apply_relu_kernel<<<(N * F_H / 4 + 255) / 256, 256, 0, stream>>>(
        out, scale2, shift2, N * F_H / 4);
}

// Round 12
// 469.073 us; speedup vs baseline: 1.2628x; 1.1029x over previous
//
#include <hip/hip_runtime.h>

#define N_NODES 200000
#define N_EDGES 1200000
#define F_IN    64
#define F_H     128
#define BN_EPS  1e-5f
#define NBUK    196          // ceil(N/1024) dst-buckets of 1024 nodes
#define BINB    293          // ceil(E/4096) bin blocks
#define BCAP    8192         // fixed bucket segment capacity (mean 6144, sigma 78)

typedef short bf16x8 __attribute__((ext_vector_type(8)));   // 8 bf16 in 4 VGPRs
typedef float f32x4  __attribute__((ext_vector_type(4)));
typedef unsigned short us4 __attribute__((ext_vector_type(4)));

__device__ __forceinline__ unsigned short f2bf(float f) {
    union { float f; unsigned u; } v; v.f = f;
    unsigned r = (v.u + 0x7FFFu + ((v.u >> 16) & 1u)) >> 16;  // RNE
    return (unsigned short)r;
}
__device__ __forceinline__ float bf2f(unsigned short b) {
    union { unsigned u; float f; } v; v.u = ((unsigned)b) << 16;
    return v.f;
}

// per-lane gather slice type: 16 lanes cover one K-row (K*2 bytes)
template<int K> struct ldsel       { using T = bf16x8; };  // K=128: 16B/lane
template<>      struct ldsel<64>   { using T = us4;    };  // K=64 :  8B/lane

// ---------------------------------------------------------------------------
// x -> bf16 convert: halves the bytes the L1 random gather must move.
// ---------------------------------------------------------------------------
__global__ __launch_bounds__(256) void cvt_bf16_kernel(
    const float* __restrict__ x, unsigned short* __restrict__ xb, int n8)
{
    int i = blockIdx.x * 256 + threadIdx.x;
    if (i >= n8) return;
    float4 a = ((const float4*)x)[i * 2];
    float4 b = ((const float4*)x)[i * 2 + 1];
    bf16x8 o;
    o[0] = (short)f2bf(a.x); o[1] = (short)f2bf(a.y);
    o[2] = (short)f2bf(a.z); o[3] = (short)f2bf(a.w);
    o[4] = (short)f2bf(b.x); o[5] = (short)f2bf(b.y);
    o[6] = (short)f2bf(b.z); o[7] = (short)f2bf(b.w);
    ((bf16x8*)xb)[i] = o;
}

// ---------------------------------------------------------------------------
// Weight pack into bf16 MFMA B-fragment order for mfma_f32_16x16x32_bf16.
// ---------------------------------------------------------------------------
__global__ void pack_weights_kernel(const float* __restrict__ W,
                                    const float* __restrict__ kscale,
                                    short* __restrict__ P, int KT)
{
    int t = blockIdx.x * 256 + threadIdx.x;            // over 8*KT*64
    if (t >= 8 * KT * 64) return;
    int lane = t & 63;
    int kt   = (t >> 6) % KT;
    int nt   = t / (64 * KT);
    int k0   = kt * 32 + (lane >> 4) * 8;
    int n    = nt * 16 + (lane & 15);
#pragma unroll
    for (int j = 0; j < 8; ++j) {
        float w = W[(size_t)(k0 + j) * 128 + n];
        if (kscale) w *= kscale[k0 + j];
        P[(size_t)t * 8 + j] = (short)f2bf(w);
    }
}

// ---------------------------------------------------------------------------
// R12 graph build: NO global hist / N-scan. Buckets get fixed-capacity
// segments in `binned` (BCAP=8192 >> max count ~6.5K); bin reserves
// against cursors initialized to b*BCAP; a 196-entry scan gives global
// rowptr bases; scatter2 does per-node hist + scan + rowptr/degf + scatter
// entirely in LDS over its L2-hot 24KB segment. Replaces the E-random-
// atomic hist_kernel and two N-length scan passes.
// ---------------------------------------------------------------------------
__global__ void binit_kernel(int* __restrict__ bcursor)
{
    bcursor[threadIdx.x] = threadIdx.x * BCAP;
}

__global__ __launch_bounds__(256) void bin_kernel(
    const int* __restrict__ ei, int* __restrict__ bcursor,
    unsigned* __restrict__ binned, int E)
{
    __shared__ int lcnt[256];
    __shared__ int lbase[256];
    __shared__ int gbase[256];
    __shared__ int sc[256];
    __shared__ unsigned stage[4096];
    __shared__ unsigned char stgb[4096];
    const int tid  = threadIdx.x;
    const int base = blockIdx.x * 4096;
    lcnt[tid] = 0;
    __syncthreads();

    unsigned val[16]; short lp[16]; unsigned char bk[16];
#pragma unroll
    for (int i = 0; i < 16; ++i) {
        int e = base + i * 256 + tid;
        if (e < E) {
            int s = ei[e], d = ei[E + e];
            int b = d >> 10;
            val[i] = ((unsigned)s << 10) | (unsigned)(d & 1023);
            bk[i]  = (unsigned char)b;
            lp[i]  = (short)atomicAdd(&lcnt[b], 1);
        } else lp[i] = -1;
    }
    __syncthreads();

    // exclusive scan of per-bucket counts + global range reservation
    int c = lcnt[tid];
    sc[tid] = c;
    __syncthreads();
    for (int off = 1; off < 256; off <<= 1) {
        int v = (tid >= off) ? sc[tid - off] : 0;
        __syncthreads();
        sc[tid] += v;
        __syncthreads();
    }
    lbase[tid] = sc[tid] - c;
    if (c) gbase[tid] = atomicAdd(&bcursor[tid], c);
    __syncthreads();
    const int total = sc[255];

    // bucket-sorted stage in LDS
#pragma unroll
    for (int i = 0; i < 16; ++i) {
        if (lp[i] >= 0) {
            int p = lbase[bk[i]] + lp[i];
            stage[p] = val[i];
            stgb[p]  = bk[i];
        }
    }
    __syncthreads();

    // write out: consecutive p within a bucket -> consecutive global addrs
    for (int p = tid; p < total; p += 256) {
        int b = stgb[p];
        binned[gbase[b] + (p - lbase[b])] = stage[p];
    }
}

// 196-entry exclusive scan of bucket counts -> global rowptr base per bucket
__global__ void scanb_kernel(const int* __restrict__ bcursor,
                             int* __restrict__ bbase)
{
    __shared__ int s[256];
    int t = threadIdx.x;
    int c = (t < NBUK) ? (bcursor[t] - t * BCAP) : 0;
    s[t] = c;
    __syncthreads();
    for (int off = 1; off < 256; off <<= 1) {
        int xv = (t >= off) ? s[t - off] : 0;
        __syncthreads();
        s[t] += xv;
        __syncthreads();
    }
    bbase[t] = s[t] - c;   // exclusive
}

// one block per bucket: LDS hist -> LDS scan -> rowptr/degf/cursors -> scatter
__global__ __launch_bounds__(256) void scatter2_kernel(
    const unsigned* __restrict__ binned, const int* __restrict__ bcursor,
    const int* __restrict__ bbase, int* __restrict__ rowptr,
    float* __restrict__ degf, int* __restrict__ ssrc)
{
    __shared__ int cnt[1024];
    __shared__ int cur[1024];
    __shared__ int s[256];
    const int b    = blockIdx.x;
    const int tid  = threadIdx.x;
    const int dbase = b << 10;
    const int segb  = b * BCAP;
    const int n     = bcursor[b] - segb;   // bucket edge count
    const int base  = bbase[b];            // global rowptr base

    for (int j = tid; j < 1024; j += 256) cnt[j] = 0;
    __syncthreads();
    for (int e = tid; e < n; e += 256)
        atomicAdd(&cnt[binned[segb + e] & 1023u], 1);
    __syncthreads();

    // exclusive scan of 1024 counts (256 threads x 4)
    int v0 = cnt[tid * 4], v1 = cnt[tid * 4 + 1];
    int v2 = cnt[tid * 4 + 2], v3 = cnt[tid * 4 + 3];
    int tsum = v0 + v1 + v2 + v3;
    s[tid] = tsum;
    __syncthreads();
    for (int off = 1; off < 256; off <<= 1) {
        int xv = (tid >= off) ? s[tid - off] : 0;
        __syncthreads();
        s[tid] += xv;
        __syncthreads();
    }
    int o0 = s[tid] - tsum;
    int o1 = o0 + v0, o2 = o1 + v1, o3 = o2 + v2;

    // rowptr / cursors / degf (rowptr is padded past N; degf guarded)
    {
        int j = tid * 4;
        rowptr[dbase + j]     = base + o0;  cur[j]     = base + o0;
        rowptr[dbase + j + 1] = base + o1;  cur[j + 1] = base + o1;
        rowptr[dbase + j + 2] = base + o2;  cur[j + 2] = base + o2;
        rowptr[dbase + j + 3] = base + o3;  cur[j + 3] = base + o3;
        if (dbase + j     < N_NODES) degf[dbase + j]     = (float)v0;
        if (dbase + j + 1 < N_NODES) degf[dbase + j + 1] = (float)v1;
        if (dbase + j + 2 < N_NODES) degf[dbase + j + 2] = (float)v2;
        if (dbase + j + 3 < N_NODES) degf[dbase + j + 3] = (float)v3;
    }
    if (b == NBUK - 1 && tid == 0) rowptr[N_NODES] = N_EDGES;
    __syncthreads();

    // scatter within the bucket (LDS cursors; writes stay in-bucket)
    for (int e = tid; e < n; e += 256) {
        unsigned v = binned[segb + e];
        int pos = atomicAdd(&cur[v & 1023u], 1);
        ssrc[pos] = (int)(v >> 10);
    }
}

// ---------------------------------------------------------------------------
// Fused SAGE layer (R11 structure, unchanged — passing at 517 us).
// 128-row blocks, 32 rows/wave, 2-stage index pipeline, bf16 gather both
// layers (L1 from pre-converted xb, L2 from t1).
// ---------------------------------------------------------------------------
template<int K, bool L2>
__global__ __launch_bounds__(256, 2) void fused_sage_kernel(
    const unsigned short* __restrict__ xgB,  // bf16 gather src + root rows
    const int* __restrict__ rowptr, const int* __restrict__ ssrc,
    const bf16x8* __restrict__ Wlp, const bf16x8* __restrict__ Wrp,
    const float* __restrict__ bias,
    const float* __restrict__ c2, const float* __restrict__ degf,
    float* __restrict__ outF, unsigned short* __restrict__ outB,
    float* __restrict__ gsum, float* __restrict__ gsq)
{
    constexpr int KT = K / 32;
    constexpr int NA = K / 16;                // bf16 elems per lane slice
    constexpr int RB = K * 2 + 16;            // padded LDS row stride (bytes)
    using ldT = typename ldsel<K>::T;
    __shared__ unsigned char sA[128 * RB];
    __shared__ float sS[128];
    __shared__ float sQ[128];

    const int tid  = threadIdx.x;
    const int lane = tid & 63;
    const int wv   = tid >> 6;
    const int m    = lane & 15;
    const int quad = lane >> 4;
    const int li   = lane & 15;
    const int sub  = lane >> 4;               // 0..3 (4 rows per gather pass)
    const int rowbase = blockIdx.x * 128 + wv * 32;

    if (tid < 128) { sS[tid] = 0.f; sQ[tid] = 0.f; }

    // ---- root-X prefetch: issued first, lands during the gather phase ----
    int rc[2];
#pragma unroll
    for (int st = 0; st < 2; ++st) {
        int r = rowbase + st * 16 + m;
        rc[st] = r < N_NODES ? r : N_NODES - 1;
    }
    bf16x8 xReg[2][KT];
#pragma unroll
    for (int st = 0; st < 2; ++st) {
        const unsigned short* xp = xgB + (size_t)rc[st] * K + quad * 8;
#pragma unroll
        for (int kt = 0; kt < KT; ++kt)
            xReg[st][kt] = *(const bf16x8*)(xp + kt * 32);
    }

    // ---- rowptr for the wave's 32 rows: one coalesced load + shfl ----
    int rpv = rowptr[min(rowbase + min(lane, 32), N_NODES)];
    int bA[8], eA[8];
#pragma unroll
    for (int g = 0; g < 8; ++g) {
        bA[g] = __shfl(rpv, g * 4 + sub);
        eA[g] = __shfl(rpv, g * 4 + sub + 1);
    }

    auto loadRow = [&](int idx) -> ldT {
        if constexpr (K == 128)
            return *(const bf16x8*)(xgB + (size_t)idx * K + li * 8);
        else
            return *(const us4*)(xgB + (size_t)idx * K + li * 4);
    };

    // ---- gather phase: 8 passes, indices prefetched one pass ahead ----
    int sN[8];
#pragma unroll
    for (int q = 0; q < 8; ++q) sN[q] = (bA[0] + q < eA[0]) ? ssrc[bA[0] + q] : 0;

    for (int g = 0; g < 8; ++g) {
        const int lrow = wv * 32 + g * 4 + sub;
        const int b = bA[g], e = eA[g];
        int sC[8];
#pragma unroll
        for (int q = 0; q < 8; ++q) sC[q] = sN[q];

        // issue this pass's feature loads
        ldT v[8];
#pragma unroll
        for (int q = 0; q < 8; ++q) v[q] = loadRow(sC[q]);
        // prefetch next pass's indices (independent — overlaps v)
        if (g < 7) {
#pragma unroll
            for (int q = 0; q < 8; ++q)
                sN[q] = (bA[g+1] + q < eA[g+1]) ? ssrc[bA[g+1] + q] : 0;
        }
        float acc[NA] = {};
#pragma unroll
        for (int q = 0; q < 8; ++q) {
            float w = (b + q < e) ? 1.f : 0.f;
#pragma unroll
            for (int k = 0; k < NA; ++k)
                acc[k] = fmaf(bf2f((unsigned short)v[q][k]), w, acc[k]);
        }
        // tail: deg > 8 (batched, as before)
        if (e > b + 8) {
            int s2[8];
#pragma unroll
            for (int q = 0; q < 8; ++q) s2[q] = (b + 8 + q < e) ? ssrc[b + 8 + q] : 0;
            for (int j = b + 8; j < e; j += 8) {
                int nn[8];
                const int jn = j + 8;
#pragma unroll
                for (int q = 0; q < 8; ++q) nn[q] = (jn + q < e) ? ssrc[jn + q] : 0;
                ldT v2[8];
#pragma unroll
                for (int q = 0; q < 8; ++q) v2[q] = loadRow(s2[q]);
#pragma unroll
                for (int q = 0; q < 8; ++q) {
                    float w = (j + q < e) ? 1.f : 0.f;
#pragma unroll
                    for (int k = 0; k < NA; ++k)
                        acc[k] = fmaf(bf2f((unsigned short)v2[q][k]), w, acc[k]);
                }
#pragma unroll
                for (int q = 0; q < 8; ++q) s2[q] = nn[q];
            }
        }
        ldT o;
#pragma unroll
        for (int k = 0; k < NA; ++k) o[k] = (short)f2bf(acc[k]);
        *(ldT*)(sA + lrow * RB + li * sizeof(ldT)) = o;
    }

    // per-nt epilogue constants (col = nt*16 + m)
    float bcol[8], ccol[8];
#pragma unroll
    for (int nt = 0; nt < 8; ++nt) {
        bcol[nt] = bias[nt * 16 + m];
        if constexpr (L2) ccol[nt] = c2[nt * 16 + m];
    }

    __syncthreads();   // A-tile complete

    // ---- A fragments from LDS (padded stride: conflict-free) ----
    bf16x8 aReg[2][KT];
#pragma unroll
    for (int st = 0; st < 2; ++st) {
        const unsigned char* ap = sA + (wv * 32 + st * 16 + m) * RB + quad * 16;
#pragma unroll
        for (int kt = 0; kt < KT; ++kt)
            aReg[st][kt] = *(const bf16x8*)(ap + kt * 64);
    }

    // ---- K loop: weights from global (L2-hot) + MFMA ----
    f32x4 acc[2][8] = {};
#pragma unroll
    for (int kt = 0; kt < KT; ++kt) {
#pragma unroll
        for (int nt = 0; nt < 8; ++nt) {
            bf16x8 wl = Wlp[(nt * KT + kt) * 64 + lane];
#pragma unroll
            for (int st = 0; st < 2; ++st)
                acc[st][nt] = __builtin_amdgcn_mfma_f32_16x16x32_bf16(
                    aReg[st][kt], wl, acc[st][nt], 0, 0, 0);
            bf16x8 wr = Wrp[(nt * KT + kt) * 64 + lane];
#pragma unroll
            for (int st = 0; st < 2; ++st)
                acc[st][nt] = __builtin_amdgcn_mfma_f32_16x16x32_bf16(
                    xReg[st][kt], wr, acc[st][nt], 0, 0, 0);
        }
    }

    // ---- epilogue: C/D layout col = lane&15, row = quad*4 + reg ----
    float stS[8] = {}, stQ[8] = {};
#pragma unroll
    for (int st = 0; st < 2; ++st) {
        const int orow = rowbase + st * 16 + quad * 4;
        float dg[4];
        if constexpr (L2) {
#pragma unroll
            for (int r = 0; r < 4; ++r) {
                int rr = orow + r;
                dg[r] = (rr < N_NODES) ? degf[rr] : 0.f;
            }
        }
#pragma unroll
        for (int nt = 0; nt < 8; ++nt) {
            int col = nt * 16 + m;
#pragma unroll
            for (int r = 0; r < 4; ++r) {
                int rr = orow + r;
                if (rr < N_NODES) {
                    float base = L2 ? fmaf(dg[r], ccol[nt], bcol[nt]) : bcol[nt];
                    float v = fmaxf(acc[st][nt][r] + base, 0.f);
                    if constexpr (L2) outF[(size_t)rr * 128 + col] = v;
                    else              outB[(size_t)rr * 128 + col] = f2bf(v);
                    stS[nt] += v;
                    stQ[nt] = fmaf(v, v, stQ[nt]);
                }
            }
        }
    }

    // ---- stats reduce: registers -> LDS -> global replica (8 replicas) ----
#pragma unroll
    for (int nt = 0; nt < 8; ++nt) {
        atomicAdd(&sS[nt * 16 + m], stS[nt]);
        atomicAdd(&sQ[nt * 16 + m], stQ[nt]);
    }
    __syncthreads();
    const int rep = (blockIdx.x & 7) * 128;
    if (tid < 128) {
        atomicAdd(&gsum[rep + tid], sS[tid]);
        atomicAdd(&gsq[rep + tid],  sQ[tid]);
    }
}

// ---------------------------------------------------------------------------
// BN finalize: per-feature scale/shift (sums the 8 stats replicas).
// ---------------------------------------------------------------------------
__global__ void bn_finalize_kernel(
    const float* __restrict__ gsum, const float* __restrict__ gsq,
    const float* __restrict__ g, const float* __restrict__ be,
    float* __restrict__ scale, float* __restrict__ shift, float invN)
{
    int c = threadIdx.x;  // 128
    float s = 0.f, q = 0.f;
#pragma unroll
    for (int k = 0; k < 8; ++k) {
        s += gsum[k * 128 + c];
        q += gsq[k * 128 + c];
    }
    float mean = s * invN;
    float var  = fmaxf(q * invN - mean * mean, 0.f);
    float sc   = g[c] * rsqrtf(var + BN_EPS);
    scale[c] = sc;
    shift[c] = be[c] - mean * sc;
}

// BN1 fold constants: c2 = shift1@W2l ; crb = shift1@W2r + b2
__global__ void bn_fold_kernel(
    const float* __restrict__ shift1, const float* __restrict__ W2l,
    const float* __restrict__ W2r, const float* __restrict__ b2,
    float* __restrict__ c2, float* __restrict__ crb)
{
    int col = threadIdx.x;  // 128
    float a = 0.f, r = 0.f;
    for (int k = 0; k < 128; ++k) {
        float s = shift1[k];
        a = fmaf(s, W2l[(size_t)k * 128 + col], a);
        r = fmaf(s, W2r[(size_t)k * 128 + col], r);
    }
    c2[col]  = a;
    crb[col] = r + b2[col];
}

// ---------------------------------------------------------------------------
// Final BN apply + ReLU (in place on d_out).
// ---------------------------------------------------------------------------
__global__ __launch_bounds__(256) void bn_apply_relu_kernel(
    float* __restrict__ h, const float* __restrict__ scale,
    const float* __restrict__ shift, int n4)
{
    int i = blockIdx.x * 256 + threadIdx.x;
    if (i >= n4) return;
    int cb = i & 31;
    float4 v  = ((float4*)h)[i];
    float4 sc = ((const float4*)scale)[cb];
    float4 sh = ((const float4*)shift)[cb];
    v.x = fmaxf(fmaf(v.x, sc.x, sh.x), 0.f);
    v.y = fmaxf(fmaf(v.y, sc.y, sh.y), 0.f);
    v.z = fmaxf(fmaf(v.z, sc.z, sh.z), 0.f);
    v.w = fmaxf(fmaf(v.w, sc.w, sh.w), 0.f);
    ((float4*)h)[i] = v;
}

extern "C" void kernel_launch(void* const* d_in, const int* in_sizes, int n_in,
                              void* d_out, int out_size, void* d_ws, size_t ws_size,
                              hipStream_t stream) {
    const float* x   = (const float*)d_in[0];
    const int*   ei  = (const int*)d_in[1];
    const float* W1l = (const float*)d_in[2];
    const float* b1  = (const float*)d_in[3];
    const float* W1r = (const float*)d_in[4];
    const float* g1  = (const float*)d_in[5];
    const float* be1 = (const float*)d_in[6];
    const float* W2l = (const float*)d_in[7];
    const float* b2  = (const float*)d_in[8];
    const float* W2r = (const float*)d_in[9];
    const float* g2  = (const float*)d_in[10];
    const float* be2 = (const float*)d_in[11];
    float* out = (float*)d_out;

    const int N = N_NODES, E = N_EDGES;
    const int nT  = (N + 127) / 128;            // 1563 fused blocks

    // Workspace layout (float units):
    float* ws     = (float*)d_ws;
    float* gsum1  = ws;          float* gsq1   = ws + 1024;   // 8 replicas x 128
    float* gsum2  = ws + 2048;   float* gsq2   = ws + 3072;
    float* scale1 = ws + 4096;   float* shift1 = ws + 4224;
    float* scale2 = ws + 4352;   float* shift2 = ws + 4480;
    float* c2v    = ws + 4608;   float* crb    = ws + 4736;
    short* W1lp = (short*)(ws + 5120);                        // 4096 f
    short* W1rp = (short*)(ws + 5120 + 4096);                 // 4096 f
    short* W2lp = (short*)(ws + 5120 + 8192);                 // 8192 f
    short* W2rp = (short*)(ws + 5120 + 16384);                // 8192 f
    int*   rowptr = (int*)(ws + 29696);                       // N+1 (pad 1024)
    int*   bcursor= rowptr + (N + 1024);                      // 256
    int*   bbase  = bcursor + 256;                            // 256
    float* degf   = (float*)(bbase + 256);                    // N
    int*   ssrc   = (int*)(degf + N);                         // E
    unsigned short* t1   = (unsigned short*)(ssrc + E);       // N*128 bf16
    unsigned* binned = (unsigned*)(t1 + (size_t)N * F_H);     // NBUK*BCAP u32
    unsigned short* xb = (unsigned short*)(binned + NBUK * BCAP); // N*64 bf16

    // ---- Graph build (no hist/N-scan) + weight pack + x->bf16 convert ----
    hipMemsetAsync(ws, 0, 4096 * sizeof(float), stream);      // stats replicas
    pack_weights_kernel<<<4, 256, 0, stream>>>(W1l, nullptr, W1lp, 2);
    pack_weights_kernel<<<4, 256, 0, stream>>>(W1r, nullptr, W1rp, 2);
    cvt_bf16_kernel<<<(N * F_IN / 8 + 255) / 256, 256, 0, stream>>>(
        x, xb, N * F_IN / 8);
    binit_kernel<<<1, 256, 0, stream>>>(bcursor);
    bin_kernel<<<BINB, 256, 0, stream>>>(ei, bcursor, binned, E);
    scanb_kernel<<<1, 256, 0, stream>>>(bcursor, bbase);
    scatter2_kernel<<<NBUK, 256, 0, stream>>>(binned, bcursor, bbase,
                                              rowptr, degf, ssrc);

    // ---- Layer 1 (fused gather + GEMM + stats; bf16 gather from xb) ----
    fused_sage_kernel<F_IN, false><<<nT, 256, 0, stream>>>(
        xb, rowptr, ssrc,
        (const bf16x8*)W1lp, (const bf16x8*)W1rp, b1,
        nullptr, nullptr, nullptr, t1, gsum1, gsq1);
    bn_finalize_kernel<<<1, 128, 0, stream>>>(gsum1, gsq1, g1, be1,
                                              scale1, shift1, 1.f / N);

    // ---- Layer 2 (BN1 folded: scale1 into weights, shift1 into c2/crb) ----
    pack_weights_kernel<<<8, 256, 0, stream>>>(W2l, scale1, W2lp, 4);
    pack_weights_kernel<<<8, 256, 0, stream>>>(W2r, scale1, W2rp, 4);
    bn_fold_kernel<<<1, 128, 0, stream>>>(shift1, W2l, W2r, b2, c2v, crb);
    fused_sage_kernel<F_H, true><<<nT, 256, 0, stream>>>(
        t1, rowptr, ssrc,
        (const bf16x8*)W2lp, (const bf16x8*)W2rp, crb,
        c2v, degf, out, nullptr, gsum2, gsq2);
    bn_finalize_kernel<<<1, 128, 0, stream>>>(gsum2, gsq2, g2, be2,
                                              scale2, shift2, 1.f / N);
    bn_apply_relu_kernel<<<(N * F_H / 4 + 255) / 256, 256, 0, stream>>>(
        out, scale2, shift2, N * F_H / 4);
}

// Round 13
// 456.132 us; speedup vs baseline: 1.2986x; 1.0284x over previous
//
#include <hip/hip_runtime.h>

#define N_NODES 200000
#define N_EDGES 1200000
#define F_IN    64
#define F_H     128
#define BN_EPS  1e-5f
#define NBUK    196          // ceil(N/1024) dst-buckets of 1024 nodes
#define BINB    293          // ceil(E/4096) bin blocks
#define BCAP    8192         // fixed bucket segment capacity (mean 6144, sigma 78)

typedef short bf16x8 __attribute__((ext_vector_type(8)));   // 8 bf16 in 4 VGPRs
typedef float f32x4  __attribute__((ext_vector_type(4)));
typedef unsigned short us4 __attribute__((ext_vector_type(4)));

__device__ __forceinline__ unsigned short f2bf(float f) {
    union { float f; unsigned u; } v; v.f = f;
    unsigned r = (v.u + 0x7FFFu + ((v.u >> 16) & 1u)) >> 16;  // RNE
    return (unsigned short)r;
}
__device__ __forceinline__ float bf2f(unsigned short b) {
    union { unsigned u; float f; } v; v.u = ((unsigned)b) << 16;
    return v.f;
}

// per-lane gather slice type: 16 lanes cover one K-row (K*2 bytes)
template<int K> struct ldsel       { using T = bf16x8; };  // K=128: 16B/lane
template<>      struct ldsel<64>   { using T = us4;    };  // K=64 :  8B/lane

// ---------------------------------------------------------------------------
// x -> bf16 convert (+ bucket-cursor init folded in: R13 dispatch merge).
// ---------------------------------------------------------------------------
__global__ __launch_bounds__(256) void cvt_bf16_kernel(
    const float* __restrict__ x, unsigned short* __restrict__ xb,
    int* __restrict__ bcursor, int n8)
{
    if (blockIdx.x == 0) bcursor[threadIdx.x] = threadIdx.x * BCAP;
    int i = blockIdx.x * 256 + threadIdx.x;
    if (i >= n8) return;
    float4 a = ((const float4*)x)[i * 2];
    float4 b = ((const float4*)x)[i * 2 + 1];
    bf16x8 o;
    o[0] = (short)f2bf(a.x); o[1] = (short)f2bf(a.y);
    o[2] = (short)f2bf(a.z); o[3] = (short)f2bf(a.w);
    o[4] = (short)f2bf(b.x); o[5] = (short)f2bf(b.y);
    o[6] = (short)f2bf(b.z); o[7] = (short)f2bf(b.w);
    ((bf16x8*)xb)[i] = o;
}

// ---------------------------------------------------------------------------
// Pack BOTH weight matrices of a layer in ONE dispatch (R13 merge).
// blocks [0, 2*KT) -> Wa/Pa ; [2*KT, 4*KT) -> Wb/Pb.
// ---------------------------------------------------------------------------
__global__ void pack2_weights_kernel(const float* __restrict__ Wa,
                                     const float* __restrict__ Wb,
                                     const float* __restrict__ kscale,
                                     short* __restrict__ Pa,
                                     short* __restrict__ Pb, int KT)
{
    const int nb = 2 * KT;
    const bool second = (int)blockIdx.x >= nb;
    const float* W = second ? Wb : Wa;
    short* P = second ? Pb : Pa;
    int t = (second ? blockIdx.x - nb : blockIdx.x) * 256 + threadIdx.x;
    if (t >= 8 * KT * 64) return;
    int lane = t & 63;
    int kt   = (t >> 6) % KT;
    int nt   = t / (64 * KT);
    int k0   = kt * 32 + (lane >> 4) * 8;
    int n    = nt * 16 + (lane & 15);
#pragma unroll
    for (int j = 0; j < 8; ++j) {
        float w = W[(size_t)(k0 + j) * 128 + n];
        if (kscale) w *= kscale[k0 + j];
        P[(size_t)t * 8 + j] = (short)f2bf(w);
    }
}

// ---------------------------------------------------------------------------
// bin_kernel: LDS multi-split of edges into 196 fixed-capacity buckets.
// ---------------------------------------------------------------------------
__global__ __launch_bounds__(256) void bin_kernel(
    const int* __restrict__ ei, int* __restrict__ bcursor,
    unsigned* __restrict__ binned, int E)
{
    __shared__ int lcnt[256];
    __shared__ int lbase[256];
    __shared__ int gbase[256];
    __shared__ int sc[256];
    __shared__ unsigned stage[4096];
    __shared__ unsigned char stgb[4096];
    const int tid  = threadIdx.x;
    const int base = blockIdx.x * 4096;
    lcnt[tid] = 0;
    __syncthreads();

    unsigned val[16]; short lp[16]; unsigned char bk[16];
#pragma unroll
    for (int i = 0; i < 16; ++i) {
        int e = base + i * 256 + tid;
        if (e < E) {
            int s = ei[e], d = ei[E + e];
            int b = d >> 10;
            val[i] = ((unsigned)s << 10) | (unsigned)(d & 1023);
            bk[i]  = (unsigned char)b;
            lp[i]  = (short)atomicAdd(&lcnt[b], 1);
        } else lp[i] = -1;
    }
    __syncthreads();

    // exclusive scan of per-bucket counts + global range reservation
    int c = lcnt[tid];
    sc[tid] = c;
    __syncthreads();
    for (int off = 1; off < 256; off <<= 1) {
        int v = (tid >= off) ? sc[tid - off] : 0;
        __syncthreads();
        sc[tid] += v;
        __syncthreads();
    }
    lbase[tid] = sc[tid] - c;
    if (c) gbase[tid] = atomicAdd(&bcursor[tid], c);
    __syncthreads();
    const int total = sc[255];

    // bucket-sorted stage in LDS
#pragma unroll
    for (int i = 0; i < 16; ++i) {
        if (lp[i] >= 0) {
            int p = lbase[bk[i]] + lp[i];
            stage[p] = val[i];
            stgb[p]  = bk[i];
        }
    }
    __syncthreads();

    // write out: consecutive p within a bucket -> consecutive global addrs
    for (int p = tid; p < total; p += 256) {
        int b = stgb[p];
        binned[gbase[b] + (p - lbase[b])] = stage[p];
    }
}

// ---------------------------------------------------------------------------
// scatter2: one block per bucket. In-block 196-entry bucket-prefix scan
// (replaces the scanb dispatch), then per-node LDS hist -> LDS scan ->
// rowptr/degf/cursors -> scatter, all over the bucket's L2-hot segment.
// ---------------------------------------------------------------------------
__global__ __launch_bounds__(256) void scatter2_kernel(
    const unsigned* __restrict__ binned, const int* __restrict__ bcursor,
    int* __restrict__ rowptr, float* __restrict__ degf, int* __restrict__ ssrc)
{
    __shared__ int cnt[1024];
    __shared__ int cur[1024];
    __shared__ int s[256];
    const int b    = blockIdx.x;
    const int tid  = threadIdx.x;
    const int dbase = b << 10;
    const int segb  = b * BCAP;
    const int n     = bcursor[b] - segb;   // bucket edge count

    // ---- in-block exclusive scan of all bucket counts -> global base ----
    int cme = (tid < NBUK) ? (bcursor[tid] - tid * BCAP) : 0;
    s[tid] = cme;
    __syncthreads();
    for (int off = 1; off < 256; off <<= 1) {
        int xv = (tid >= off) ? s[tid - off] : 0;
        __syncthreads();
        s[tid] += xv;
        __syncthreads();
    }
    const int base = s[b] - n;             // exclusive prefix at bucket b

    for (int j = tid; j < 1024; j += 256) cnt[j] = 0;
    __syncthreads();
    for (int e = tid; e < n; e += 256)
        atomicAdd(&cnt[binned[segb + e] & 1023u], 1);
    __syncthreads();

    // exclusive scan of 1024 counts (256 threads x 4)
    int v0 = cnt[tid * 4], v1 = cnt[tid * 4 + 1];
    int v2 = cnt[tid * 4 + 2], v3 = cnt[tid * 4 + 3];
    int tsum = v0 + v1 + v2 + v3;
    s[tid] = tsum;
    __syncthreads();
    for (int off = 1; off < 256; off <<= 1) {
        int xv = (tid >= off) ? s[tid - off] : 0;
        __syncthreads();
        s[tid] += xv;
        __syncthreads();
    }
    int o0 = s[tid] - tsum;
    int o1 = o0 + v0, o2 = o1 + v1, o3 = o2 + v2;

    // rowptr / cursors / degf (rowptr is padded past N; degf guarded)
    {
        int j = tid * 4;
        rowptr[dbase + j]     = base + o0;  cur[j]     = base + o0;
        rowptr[dbase + j + 1] = base + o1;  cur[j + 1] = base + o1;
        rowptr[dbase + j + 2] = base + o2;  cur[j + 2] = base + o2;
        rowptr[dbase + j + 3] = base + o3;  cur[j + 3] = base + o3;
        if (dbase + j     < N_NODES) degf[dbase + j]     = (float)v0;
        if (dbase + j + 1 < N_NODES) degf[dbase + j + 1] = (float)v1;
        if (dbase + j + 2 < N_NODES) degf[dbase + j + 2] = (float)v2;
        if (dbase + j + 3 < N_NODES) degf[dbase + j + 3] = (float)v3;
    }
    if (b == NBUK - 1 && tid == 0) rowptr[N_NODES] = N_EDGES;
    __syncthreads();

    // scatter within the bucket (LDS cursors; writes stay in-bucket)
    for (int e = tid; e < n; e += 256) {
        unsigned v = binned[segb + e];
        int pos = atomicAdd(&cur[v & 1023u], 1);
        ssrc[pos] = (int)(v >> 10);
    }
}

// ---------------------------------------------------------------------------
// Fused SAGE layer (unchanged from R11/R12 — passing).
// 128-row blocks, 32 rows/wave, 2-stage index pipeline, bf16 gather both
// layers (L1 from pre-converted xb, L2 from t1).
// ---------------------------------------------------------------------------
template<int K, bool L2>
__global__ __launch_bounds__(256, 2) void fused_sage_kernel(
    const unsigned short* __restrict__ xgB,  // bf16 gather src + root rows
    const int* __restrict__ rowptr, const int* __restrict__ ssrc,
    const bf16x8* __restrict__ Wlp, const bf16x8* __restrict__ Wrp,
    const float* __restrict__ bias,
    const float* __restrict__ c2, const float* __restrict__ degf,
    float* __restrict__ outF, unsigned short* __restrict__ outB,
    float* __restrict__ gsum, float* __restrict__ gsq)
{
    constexpr int KT = K / 32;
    constexpr int NA = K / 16;                // bf16 elems per lane slice
    constexpr int RB = K * 2 + 16;            // padded LDS row stride (bytes)
    using ldT = typename ldsel<K>::T;
    __shared__ unsigned char sA[128 * RB];
    __shared__ float sS[128];
    __shared__ float sQ[128];

    const int tid  = threadIdx.x;
    const int lane = tid & 63;
    const int wv   = tid >> 6;
    const int m    = lane & 15;
    const int quad = lane >> 4;
    const int li   = lane & 15;
    const int sub  = lane >> 4;               // 0..3 (4 rows per gather pass)
    const int rowbase = blockIdx.x * 128 + wv * 32;

    if (tid < 128) { sS[tid] = 0.f; sQ[tid] = 0.f; }

    // ---- root-X prefetch: issued first, lands during the gather phase ----
    int rc[2];
#pragma unroll
    for (int st = 0; st < 2; ++st) {
        int r = rowbase + st * 16 + m;
        rc[st] = r < N_NODES ? r : N_NODES - 1;
    }
    bf16x8 xReg[2][KT];
#pragma unroll
    for (int st = 0; st < 2; ++st) {
        const unsigned short* xp = xgB + (size_t)rc[st] * K + quad * 8;
#pragma unroll
        for (int kt = 0; kt < KT; ++kt)
            xReg[st][kt] = *(const bf16x8*)(xp + kt * 32);
    }

    // ---- rowptr for the wave's 32 rows: one coalesced load + shfl ----
    int rpv = rowptr[min(rowbase + min(lane, 32), N_NODES)];
    int bA[8], eA[8];
#pragma unroll
    for (int g = 0; g < 8; ++g) {
        bA[g] = __shfl(rpv, g * 4 + sub);
        eA[g] = __shfl(rpv, g * 4 + sub + 1);
    }

    auto loadRow = [&](int idx) -> ldT {
        if constexpr (K == 128)
            return *(const bf16x8*)(xgB + (size_t)idx * K + li * 8);
        else
            return *(const us4*)(xgB + (size_t)idx * K + li * 4);
    };

    // ---- gather phase: 8 passes, indices prefetched one pass ahead ----
    int sN[8];
#pragma unroll
    for (int q = 0; q < 8; ++q) sN[q] = (bA[0] + q < eA[0]) ? ssrc[bA[0] + q] : 0;

    for (int g = 0; g < 8; ++g) {
        const int lrow = wv * 32 + g * 4 + sub;
        const int b = bA[g], e = eA[g];
        int sC[8];
#pragma unroll
        for (int q = 0; q < 8; ++q) sC[q] = sN[q];

        // issue this pass's feature loads
        ldT v[8];
#pragma unroll
        for (int q = 0; q < 8; ++q) v[q] = loadRow(sC[q]);
        // prefetch next pass's indices (independent — overlaps v)
        if (g < 7) {
#pragma unroll
            for (int q = 0; q < 8; ++q)
                sN[q] = (bA[g+1] + q < eA[g+1]) ? ssrc[bA[g+1] + q] : 0;
        }
        float acc[NA] = {};
#pragma unroll
        for (int q = 0; q < 8; ++q) {
            float w = (b + q < e) ? 1.f : 0.f;
#pragma unroll
            for (int k = 0; k < NA; ++k)
                acc[k] = fmaf(bf2f((unsigned short)v[q][k]), w, acc[k]);
        }
        // tail: deg > 8 (batched, as before)
        if (e > b + 8) {
            int s2[8];
#pragma unroll
            for (int q = 0; q < 8; ++q) s2[q] = (b + 8 + q < e) ? ssrc[b + 8 + q] : 0;
            for (int j = b + 8; j < e; j += 8) {
                int nn[8];
                const int jn = j + 8;
#pragma unroll
                for (int q = 0; q < 8; ++q) nn[q] = (jn + q < e) ? ssrc[jn + q] : 0;
                ldT v2[8];
#pragma unroll
                for (int q = 0; q < 8; ++q) v2[q] = loadRow(s2[q]);
#pragma unroll
                for (int q = 0; q < 8; ++q) {
                    float w = (j + q < e) ? 1.f : 0.f;
#pragma unroll
                    for (int k = 0; k < NA; ++k)
                        acc[k] = fmaf(bf2f((unsigned short)v2[q][k]), w, acc[k]);
                }
#pragma unroll
                for (int q = 0; q < 8; ++q) s2[q] = nn[q];
            }
        }
        ldT o;
#pragma unroll
        for (int k = 0; k < NA; ++k) o[k] = (short)f2bf(acc[k]);
        *(ldT*)(sA + lrow * RB + li * sizeof(ldT)) = o;
    }

    // per-nt epilogue constants (col = nt*16 + m)
    float bcol[8], ccol[8];
#pragma unroll
    for (int nt = 0; nt < 8; ++nt) {
        bcol[nt] = bias[nt * 16 + m];
        if constexpr (L2) ccol[nt] = c2[nt * 16 + m];
    }

    __syncthreads();   // A-tile complete

    // ---- A fragments from LDS (padded stride: conflict-free) ----
    bf16x8 aReg[2][KT];
#pragma unroll
    for (int st = 0; st < 2; ++st) {
        const unsigned char* ap = sA + (wv * 32 + st * 16 + m) * RB + quad * 16;
#pragma unroll
        for (int kt = 0; kt < KT; ++kt)
            aReg[st][kt] = *(const bf16x8*)(ap + kt * 64);
    }

    // ---- K loop: weights from global (L2-hot) + MFMA ----
    f32x4 acc[2][8] = {};
#pragma unroll
    for (int kt = 0; kt < KT; ++kt) {
#pragma unroll
        for (int nt = 0; nt < 8; ++nt) {
            bf16x8 wl = Wlp[(nt * KT + kt) * 64 + lane];
#pragma unroll
            for (int st = 0; st < 2; ++st)
                acc[st][nt] = __builtin_amdgcn_mfma_f32_16x16x32_bf16(
                    aReg[st][kt], wl, acc[st][nt], 0, 0, 0);
            bf16x8 wr = Wrp[(nt * KT + kt) * 64 + lane];
#pragma unroll
            for (int st = 0; st < 2; ++st)
                acc[st][nt] = __builtin_amdgcn_mfma_f32_16x16x32_bf16(
                    xReg[st][kt], wr, acc[st][nt], 0, 0, 0);
        }
    }

    // ---- epilogue: C/D layout col = lane&15, row = quad*4 + reg ----
    float stS[8] = {}, stQ[8] = {};
#pragma unroll
    for (int st = 0; st < 2; ++st) {
        const int orow = rowbase + st * 16 + quad * 4;
        float dg[4];
        if constexpr (L2) {
#pragma unroll
            for (int r = 0; r < 4; ++r) {
                int rr = orow + r;
                dg[r] = (rr < N_NODES) ? degf[rr] : 0.f;
            }
        }
#pragma unroll
        for (int nt = 0; nt < 8; ++nt) {
            int col = nt * 16 + m;
#pragma unroll
            for (int r = 0; r < 4; ++r) {
                int rr = orow + r;
                if (rr < N_NODES) {
                    float base = L2 ? fmaf(dg[r], ccol[nt], bcol[nt]) : bcol[nt];
                    float v = fmaxf(acc[st][nt][r] + base, 0.f);
                    if constexpr (L2) outF[(size_t)rr * 128 + col] = v;
                    else              outB[(size_t)rr * 128 + col] = f2bf(v);
                    stS[nt] += v;
                    stQ[nt] = fmaf(v, v, stQ[nt]);
                }
            }
        }
    }

    // ---- stats reduce: registers -> LDS -> global replica (8 replicas) ----
#pragma unroll
    for (int nt = 0; nt < 8; ++nt) {
        atomicAdd(&sS[nt * 16 + m], stS[nt]);
        atomicAdd(&sQ[nt * 16 + m], stQ[nt]);
    }
    __syncthreads();
    const int rep = (blockIdx.x & 7) * 128;
    if (tid < 128) {
        atomicAdd(&gsum[rep + tid], sS[tid]);
        atomicAdd(&gsq[rep + tid],  sQ[tid]);
    }
}

// ---------------------------------------------------------------------------
// BN1 finalize + fold in ONE dispatch (R13 merge): scale1 -> global (pack2
// needs it); shift1 stays in LDS and folds into c2/crb right here.
// ---------------------------------------------------------------------------
__global__ void bn_ff1_kernel(
    const float* __restrict__ gsum, const float* __restrict__ gsq,
    const float* __restrict__ g, const float* __restrict__ be,
    const float* __restrict__ W2l, const float* __restrict__ W2r,
    const float* __restrict__ b2,
    float* __restrict__ scale, float* __restrict__ c2,
    float* __restrict__ crb, float invN)
{
    __shared__ float sh[128];
    int c = threadIdx.x;  // 128
    float s = 0.f, q = 0.f;
#pragma unroll
    for (int k = 0; k < 8; ++k) {
        s += gsum[k * 128 + c];
        q += gsq[k * 128 + c];
    }
    float mean = s * invN;
    float var  = fmaxf(q * invN - mean * mean, 0.f);
    float sc   = g[c] * rsqrtf(var + BN_EPS);
    scale[c] = sc;
    sh[c] = be[c] - mean * sc;
    __syncthreads();
    float a = 0.f, r = 0.f;
    for (int k = 0; k < 128; ++k) {
        float sk = sh[k];
        a = fmaf(sk, W2l[(size_t)k * 128 + c], a);
        r = fmaf(sk, W2r[(size_t)k * 128 + c], r);
    }
    c2[c]  = a;
    crb[c] = r + b2[c];
}

// ---------------------------------------------------------------------------
// BN2 finalize + apply + ReLU in ONE dispatch (R13 merge): every block
// redundantly reduces the 8x128 stats replicas (8 KB, L2-hot) into LDS
// scale/shift, then applies in place on d_out.
// ---------------------------------------------------------------------------
__global__ __launch_bounds__(256) void bn_apply2_kernel(
    const float* __restrict__ gsum, const float* __restrict__ gsq,
    const float* __restrict__ g, const float* __restrict__ be,
    float* __restrict__ h, float invN, int n4)
{
    __shared__ float ssc[128], ssh[128];
    int tid = threadIdx.x;
    if (tid < 128) {
        float s = 0.f, q = 0.f;
#pragma unroll
        for (int k = 0; k < 8; ++k) {
            s += gsum[k * 128 + tid];
            q += gsq[k * 128 + tid];
        }
        float mean = s * invN;
        float var  = fmaxf(q * invN - mean * mean, 0.f);
        float sc   = g[tid] * rsqrtf(var + BN_EPS);
        ssc[tid] = sc;
        ssh[tid] = be[tid] - mean * sc;
    }
    __syncthreads();
    int i = blockIdx.x * 256 + tid;
    if (i >= n4) return;
    int cb = (i & 31) * 4;
    float4 v = ((float4*)h)[i];
    v.x = fmaxf(fmaf(v.x, ssc[cb],     ssh[cb]),     0.f);
    v.y = fmaxf(fmaf(v.y, ssc[cb + 1], ssh[cb + 1]), 0.f);
    v.z = fmaxf(fmaf(v.z, ssc[cb + 2], ssh[cb + 2]), 0.f);
    v.w = fmaxf(fmaf(v.w, ssc[cb + 3], ssh[cb + 3]), 0.f);
    ((float4*)h)[i] = v;
}

extern "C" void kernel_launch(void* const* d_in, const int* in_sizes, int n_in,
                              void* d_out, int out_size, void* d_ws, size_t ws_size,
                              hipStream_t stream) {
    const float* x   = (const float*)d_in[0];
    const int*   ei  = (const int*)d_in[1];
    const float* W1l = (const float*)d_in[2];
    const float* b1  = (const float*)d_in[3];
    const float* W1r = (const float*)d_in[4];
    const float* g1  = (const float*)d_in[5];
    const float* be1 = (const float*)d_in[6];
    const float* W2l = (const float*)d_in[7];
    const float* b2  = (const float*)d_in[8];
    const float* W2r = (const float*)d_in[9];
    const float* g2  = (const float*)d_in[10];
    const float* be2 = (const float*)d_in[11];
    float* out = (float*)d_out;

    const int N = N_NODES, E = N_EDGES;
    const int nT  = (N + 127) / 128;            // 1563 fused blocks

    // Workspace layout (float units):
    float* ws     = (float*)d_ws;
    float* gsum1  = ws;          float* gsq1   = ws + 1024;   // 8 replicas x 128
    float* gsum2  = ws + 2048;   float* gsq2   = ws + 3072;
    float* scale1 = ws + 4096;
    float* c2v    = ws + 4608;   float* crb    = ws + 4736;
    short* W1lp = (short*)(ws + 5120);                        // 4096 f
    short* W1rp = (short*)(ws + 5120 + 4096);                 // 4096 f
    short* W2lp = (short*)(ws + 5120 + 8192);                 // 8192 f
    short* W2rp = (short*)(ws + 5120 + 16384);                // 8192 f
    int*   rowptr = (int*)(ws + 29696);                       // N+1 (pad 1024)
    int*   bcursor= rowptr + (N + 1024);                      // 256
    float* degf   = (float*)(bcursor + 256);                  // N
    int*   ssrc   = (int*)(degf + N);                         // E
    unsigned short* t1   = (unsigned short*)(ssrc + E);       // N*128 bf16
    unsigned* binned = (unsigned*)(t1 + (size_t)N * F_H);     // NBUK*BCAP u32
    unsigned short* xb = (unsigned short*)(binned + NBUK * BCAP); // N*64 bf16

    // ---- Graph build + weight pack + x->bf16 convert (10 dispatches) ----
    hipMemsetAsync(ws, 0, 4096 * sizeof(float), stream);      // stats replicas
    pack2_weights_kernel<<<8, 256, 0, stream>>>(W1l, W1r, nullptr,
                                                W1lp, W1rp, 2);
    cvt_bf16_kernel<<<(N * F_IN / 8 + 255) / 256, 256, 0, stream>>>(
        x, xb, bcursor, N * F_IN / 8);
    bin_kernel<<<BINB, 256, 0, stream>>>(ei, bcursor, binned, E);
    scatter2_kernel<<<NBUK, 256, 0, stream>>>(binned, bcursor,
                                              rowptr, degf, ssrc);

    // ---- Layer 1 (fused gather + GEMM + stats; bf16 gather from xb) ----
    fused_sage_kernel<F_IN, false><<<nT, 256, 0, stream>>>(
        xb, rowptr, ssrc,
        (const bf16x8*)W1lp, (const bf16x8*)W1rp, b1,
        nullptr, nullptr, nullptr, t1, gsum1, gsq1);
    bn_ff1_kernel<<<1, 128, 0, stream>>>(gsum1, gsq1, g1, be1,
                                         W2l, W2r, b2,
                                         scale1, c2v, crb, 1.f / N);

    // ---- Layer 2 (BN1 folded: scale1 into weights, shift1 into c2/crb) ----
    pack2_weights_kernel<<<16, 256, 0, stream>>>(W2l, W2r, scale1,
                                                 W2lp, W2rp, 4);
    fused_sage_kernel<F_H, true><<<nT, 256, 0, stream>>>(
        t1, rowptr, ssrc,
        (const bf16x8*)W2lp, (const bf16x8*)W2rp, crb,
        c2v, degf, out, nullptr, gsum2, gsq2);
    bn_apply2_kernel<<<(N * F_H / 4 + 255) / 256, 256, 0, stream>>>(
        gsum2, gsq2, g2, be2, out, 1.f / N, N * F_H / 4);
}